// Round 3
// baseline (1108.956 us; speedup 1.0000x reference)
//
#include <hip/hip_runtime.h>
#include <hip/hip_bf16.h>
#include <math.h>

#define NN 30000
#define EE 400000
#define INP 128
#define HH 4
#define DD 64
#define CC 40
#define HD 256   // H*D
#define HC 160   // H*C

typedef unsigned short ushort;
typedef __attribute__((ext_vector_type(8))) short s8v;   // 8 x bf16 bits (4 VGPRs)
typedef __attribute__((ext_vector_type(4))) float f4v;   // MFMA accumulator

// ---------------- input dtype probe ----------------
// Interpret first 128 ushorts of x as bf16. Genuine bf16 N(0,1) data: no absurd
// exponents. fp32 data read as ushorts: even indices are raw mantissa bits ->
// ~50% absurd exponents. Deterministic (same data every call).
__device__ inline int detect_fp32(const ushort* xp) {
    int cnt = 0;
    for (int i = 0; i < 128; i++) {
        ushort u = xp[i];
        int e = (u >> 7) & 0xFF;
        int man = u & 0x7F;
        if (e >= 0xC0 || (e <= 0x3F && (e > 0 || man != 0))) cnt++;
    }
    return cnt >= 8;
}

__device__ inline ushort bf16_of_float(float f) {
    __hip_bfloat16 b = __float2bfloat16(f);
    return *(ushort*)&b;
}

// canonicalize x (or any big float tensor) to bf16
__global__ __launch_bounds__(256) void k_cast(const void* __restrict__ in, ushort* __restrict__ out,
                                              int n, const ushort* __restrict__ xp) {
    __shared__ int isf;
    if (threadIdx.x == 0) isf = detect_fp32(xp);
    __syncthreads();
    int i = blockIdx.x * 256 + threadIdx.x;
    if (i < n) {
        out[i] = isf ? bf16_of_float(((const float*)in)[i]) : ((const ushort*)in)[i];
    }
}

// canonicalize the 10 small vectors into one packed bf16 buffer
// layout: b0[256] attn0[256] b1[256] attn1[256] b2[160] attn2[160] g0[256] be0[256] g1[256] be1[256]
__global__ __launch_bounds__(256) void k_cast_small(const void* b0, const void* a0, const void* b1,
                                                    const void* a1, const void* b2, const void* a2,
                                                    const void* g0, const void* be0, const void* g1,
                                                    const void* be1, ushort* __restrict__ out,
                                                    const ushort* __restrict__ xp) {
    __shared__ int isf;
    if (threadIdx.x == 0) isf = detect_fp32(xp);
    __syncthreads();
    const void* ptrs[10] = {b0, a0, b1, a1, b2, a2, g0, be0, g1, be1};
    const int sz[10] = {256, 256, 256, 256, 160, 160, 256, 256, 256, 256};
    int off = 0, t = threadIdx.x;
    for (int j = 0; j < 10; j++) {
        if (t < sz[j]) {
            out[off + t] = isf ? bf16_of_float(((const float*)ptrs[j])[t])
                               : ((const ushort*)ptrs[j])[t];
        }
        off += sz[j];
    }
}

// ---------------- CSR build ----------------

__global__ __launch_bounds__(256) void k_hist(const int* __restrict__ dst, int* __restrict__ cnt) {
    int e = blockIdx.x * 256 + threadIdx.x;
    if (e < EE) atomicAdd(&cnt[dst[e]], 1);
}

__global__ __launch_bounds__(1024) void k_scan(const int* __restrict__ cnt, int* __restrict__ indptr) {
    __shared__ int ss[1024];
    int t = threadIdx.x;
    const int CH = 30;                    // 1024*30 >= 30000
    int b = t * CH;
    int e2 = min(NN, b + CH);
    int s = 0;
    for (int i = b; i < e2; i++) s += cnt[i];
    ss[t] = s;
    __syncthreads();
    for (int o = 1; o < 1024; o <<= 1) {
        int v = (t >= o) ? ss[t - o] : 0;
        __syncthreads();
        ss[t] += v;
        __syncthreads();
    }
    int run = ss[t] - s;                  // exclusive prefix
    for (int i = b; i < e2; i++) { indptr[i] = run; run += cnt[i]; }
    if (t == 0) indptr[NN] = EE;
}

__global__ __launch_bounds__(256) void k_scatter(const int* __restrict__ src, const int* __restrict__ dst,
                                                 const int* __restrict__ indptr, int* __restrict__ pos,
                                                 int* __restrict__ srcs) {
    int e = blockIdx.x * 256 + threadIdx.x;
    if (e < EE) {
        int d = dst[e];
        int p = atomicAdd(&pos[d], 1);
        srcs[indptr[d] + p] = src[e];     // src ids grouped by dst
    }
}

// ---------------- weight transpose (W[K,No] -> Bt[Nopad,K] bf16, zero-pad rows) ----------------

__global__ __launch_bounds__(256) void k_transpose(const void* __restrict__ W, ushort* __restrict__ Bt,
                                                   int K, int No, int Nopad,
                                                   const ushort* __restrict__ xp) {
    __shared__ int isf;
    if (threadIdx.x == 0) isf = detect_fp32(xp);
    __syncthreads();
    int i = blockIdx.x * 256 + threadIdx.x;
    if (i < Nopad * K) {
        int n = i / K, k = i - n * K;
        ushort v = 0;
        if (n < No) {
            v = isf ? bf16_of_float(((const float*)W)[k * No + n])
                    : ((const ushort*)W)[k * No + n];
        }
        Bt[i] = v;
    }
}

// ---------------- bf16 MFMA GEMM: C[M,No] (fp32) = A[M,K] @ Bt[.,K]^T ----------------
// one wave per 16x64 tile; A frag: A[m=lane&15][k=quad*8+j]; B frag from Bt rows (contiguous k)

__global__ __launch_bounds__(64) void k_gemm(const ushort* __restrict__ A, const ushort* __restrict__ Bt,
                                             float* __restrict__ Cmat, int K, int No) {
    int lane = threadIdx.x;
    int m = lane & 15, q = lane >> 4;
    int row0 = blockIdx.x * 16;
    int col0 = blockIdx.y * 64;
    f4v acc[4] = {};
    const ushort* Arow = A + (size_t)(row0 + m) * K + q * 8;
    for (int kt = 0; kt < K; kt += 32) {
        s8v a = *(const s8v*)(Arow + kt);
#pragma unroll
        for (int c = 0; c < 4; c++) {
            const ushort* Brow = Bt + (size_t)(col0 + c * 16 + m) * K + q * 8 + kt;
            s8v b = *(const s8v*)Brow;
            acc[c] = __builtin_amdgcn_mfma_f32_16x16x32_bf16(a, b, acc[c], 0, 0, 0);
        }
    }
#pragma unroll
    for (int c = 0; c < 4; c++) {
        int col = col0 + c * 16 + m;
        if (col < No) {
#pragma unroll
            for (int r = 0; r < 4; r++)
                Cmat[(size_t)(row0 + q * 4 + r) * No + col] = acc[c][r];
        }
    }
}

// ---------------- fused GATv2 edge phase: online segment-softmax + aggregation ----------------
// one wave per (dst node, head); lanes = feature dim (Dh <= 64)

__global__ __launch_bounds__(256) void k_aggregate(const float* __restrict__ fs, const float* __restrict__ fd,
                                                   const float* __restrict__ res,
                                                   const __hip_bfloat16* __restrict__ attn,
                                                   const __hip_bfloat16* __restrict__ bias,
                                                   const int* __restrict__ indptr, const int* __restrict__ srcs,
                                                   float* __restrict__ out, int Dh, int do_relu) {
    int v = blockIdx.x;
    int h = threadIdx.x >> 6;
    int lane = threadIdx.x & 63;
    int F = HH * Dh;
    bool act = lane < Dh;
    int base = v * F + h * Dh;
    float fdv = act ? fd[base + lane] : 0.f;
    float av  = act ? __bfloat162float(attn[h * Dh + lane]) : 0.f;
    float mmax = -1e30f, l = 0.f, acc = 0.f;   // finite init: exp(-1e30-s)==0 even w/ fast-math
    int beg = indptr[v], end = indptr[v + 1];
    for (int i = beg; i < end; i++) {
        int u = srcs[i];
        float fsu = act ? fs[(size_t)u * F + h * Dh + lane] : 0.f;
        float t = fsu + fdv;
        t = t > 0.f ? t : 0.2f * t;          // leaky_relu slope 0.2
        float p = av * t;
#pragma unroll
        for (int o = 32; o > 0; o >>= 1) p += __shfl_xor(p, o, 64);
        float s = p;                          // score, all lanes
        float mn = fmaxf(mmax, s);
        float sc = __expf(mmax - mn);
        float w  = __expf(s - mn);
        l   = l * sc + w;
        acc = acc * sc + w * fsu;
        mmax = mn;
    }
    if (act) {
        float r = acc / fmaxf(l, 1e-9f);      // matches ref: zero in-degree -> 0
        float o = r + res[base + lane] + __bfloat162float(bias[h * Dh + lane]);
        if (do_relu) o = fmaxf(o, 0.f);
        out[base + lane] = o;
    }
}

// ---------------- batchnorm (training stats, biased var) ----------------

__global__ __launch_bounds__(256) void k_bn_partial(const float* __restrict__ h, float* __restrict__ sum,
                                                    float* __restrict__ sumsq) {
    int c = threadIdx.x;                      // channel
    int r0 = blockIdx.x * 128;
    int r1 = min(NN, r0 + 128);
    float s = 0.f, ss = 0.f;
    for (int r = r0; r < r1; r++) {
        float vv = h[(size_t)r * HD + c];
        s += vv; ss += vv * vv;
    }
    atomicAdd(&sum[c], s);
    atomicAdd(&sumsq[c], ss);
}

__global__ __launch_bounds__(256) void k_bn_norm(const float* __restrict__ hin, const float* __restrict__ sum,
                                                 const float* __restrict__ sumsq,
                                                 const __hip_bfloat16* __restrict__ g,
                                                 const __hip_bfloat16* __restrict__ be,
                                                 float* __restrict__ hout, ushort* __restrict__ hbf) {
    int idx = blockIdx.x * 256 + threadIdx.x;
    if (idx < NN * HD) {
        int c = idx & (HD - 1);
        float mean = sum[c] * (1.0f / NN);
        float var = fmaxf(sumsq[c] * (1.0f / NN) - mean * mean, 0.f);
        float y = __bfloat162float(g[c]) * (hin[idx] - mean) * rsqrtf(var + 1e-5f) + __bfloat162float(be[c]);
        y = fmaxf(y, 0.f);                    // relu after BN
        hout[idx] = y;
        hbf[idx] = bf16_of_float(y);
    }
}

// ---------------- head-mean + log_softmax (OUTPUT IS FLOAT32) ----------------

__global__ __launch_bounds__(256) void k_final(const float* __restrict__ o2, float* __restrict__ out) {
    int v = blockIdx.x * 4 + (threadIdx.x >> 6);
    int lane = threadIdx.x & 63;
    bool act = lane < CC;
    float z = -1e30f;
    if (act) {
        const float* p = o2 + (size_t)v * HC;
        z = 0.25f * (p[lane] + p[CC + lane] + p[2 * CC + lane] + p[3 * CC + lane]);
    }
    float mx = z;
#pragma unroll
    for (int o = 32; o > 0; o >>= 1) mx = fmaxf(mx, __shfl_xor(mx, o, 64));
    float ex = act ? __expf(z - mx) : 0.f;
    float l = ex;
#pragma unroll
    for (int o = 32; o > 0; o >>= 1) l += __shfl_xor(l, o, 64);
    if (act) out[(size_t)v * CC + lane] = z - mx - logf(fmaxf(l, 1e-30f));
}

// ---------------- driver ----------------

static inline char* alignup(char* p) { return (char*)(((size_t)p + 255) & ~(size_t)255); }

extern "C" void kernel_launch(void* const* d_in, const int* in_sizes, int n_in,
                              void* d_out, int out_size, void* d_ws, size_t ws_size,
                              hipStream_t stream) {
    const ushort* xprobe = (const ushort*)d_in[0];   // dtype probe source
    const void* x     = d_in[0];
    const int*  src   = (const int*)d_in[1];
    const int*  dst   = (const int*)d_in[2];
    const void* Wsrc0 = d_in[3];
    const void* Wdst0 = d_in[4];
    const void* b0    = d_in[5];
    const void* attn0 = d_in[6];
    const void* resW0 = d_in[7];
    const void* Wsrc1 = d_in[8];
    const void* Wdst1 = d_in[9];
    const void* b1    = d_in[10];
    const void* attn1 = d_in[11];
    const void* Wsrc2 = d_in[12];
    const void* Wdst2 = d_in[13];
    const void* b2    = d_in[14];
    const void* attn2 = d_in[15];
    const void* resW2 = d_in[16];
    const void* g0    = d_in[17];
    const void* be0   = d_in[18];
    const void* g1    = d_in[19];
    const void* be1   = d_in[20];

    char* w = (char*)d_ws;
    const size_t NF = (size_t)NN * HD;   // 7,680,000
    float* hA  = (float*)w;  w += NF * 4;
    float* hB  = (float*)w;  w += NF * 4;
    float* fs  = (float*)w;  w += NF * 4;
    float* fd  = (float*)w;  w += NF * 4;
    float* res = (float*)w;  w += NF * 4;
    float* bnsum = (float*)w; w += 256 * 4;
    float* bnsq  = (float*)w; w += 256 * 4;
    ushort* hbf = (ushort*)w; w += NF * 2;
    ushort* xc  = (ushort*)w; w += (size_t)NN * INP * 2;
    ushort* Bt0s = (ushort*)w; w += 256 * 128 * 2;
    ushort* Bt0d = (ushort*)w; w += 256 * 128 * 2;
    ushort* Bt0r = (ushort*)w; w += 256 * 128 * 2;
    ushort* Bt1s = (ushort*)w; w += 256 * 256 * 2;
    ushort* Bt1d = (ushort*)w; w += 256 * 256 * 2;
    ushort* Bt2s = (ushort*)w; w += 192 * 256 * 2;
    ushort* Bt2d = (ushort*)w; w += 192 * 256 * 2;
    ushort* Bt2r = (ushort*)w; w += 192 * 256 * 2;
    ushort* smallv = (ushort*)w; w += 2368 * 2; w = alignup(w);
    int* indptr = (int*)w; w += (NN + 1) * 4; w = alignup(w);
    int* cnt    = (int*)w; w += NN * 4; w = alignup(w);
    int* pos    = (int*)w; w += NN * 4; w = alignup(w);
    int* srcs   = (int*)w; w += EE * 4;

    // packed small-vector offsets (bf16 canonical)
    const __hip_bfloat16* c_b0    = (const __hip_bfloat16*)(smallv + 0);
    const __hip_bfloat16* c_attn0 = (const __hip_bfloat16*)(smallv + 256);
    const __hip_bfloat16* c_b1    = (const __hip_bfloat16*)(smallv + 512);
    const __hip_bfloat16* c_attn1 = (const __hip_bfloat16*)(smallv + 768);
    const __hip_bfloat16* c_b2    = (const __hip_bfloat16*)(smallv + 1024);
    const __hip_bfloat16* c_attn2 = (const __hip_bfloat16*)(smallv + 1184);
    const __hip_bfloat16* c_g0    = (const __hip_bfloat16*)(smallv + 1344);
    const __hip_bfloat16* c_be0   = (const __hip_bfloat16*)(smallv + 1600);
    const __hip_bfloat16* c_g1    = (const __hip_bfloat16*)(smallv + 1856);
    const __hip_bfloat16* c_be1   = (const __hip_bfloat16*)(smallv + 2112);

    // dtype canonicalization
    k_cast<<<(NN * INP + 255) / 256, 256, 0, stream>>>(x, xc, NN * INP, xprobe);
    k_cast_small<<<1, 256, 0, stream>>>(b0, attn0, b1, attn1, b2, attn2, g0, be0, g1, be1,
                                        smallv, xprobe);

    // CSR build (graph identical for all 3 layers)
    hipMemsetAsync(cnt, 0, NN * 4, stream);
    hipMemsetAsync(pos, 0, NN * 4, stream);
    k_hist<<<(EE + 255) / 256, 256, 0, stream>>>(dst, cnt);
    k_scan<<<1, 1024, 0, stream>>>(cnt, indptr);
    k_scatter<<<(EE + 255) / 256, 256, 0, stream>>>(src, dst, indptr, pos, srcs);

    // weight transposes -> bf16 canonical (padded rows for No=160)
    k_transpose<<<(256 * 128 + 255) / 256, 256, 0, stream>>>(Wsrc0, Bt0s, 128, 256, 256, xprobe);
    k_transpose<<<(256 * 128 + 255) / 256, 256, 0, stream>>>(Wdst0, Bt0d, 128, 256, 256, xprobe);
    k_transpose<<<(256 * 128 + 255) / 256, 256, 0, stream>>>(resW0, Bt0r, 128, 256, 256, xprobe);
    k_transpose<<<(256 * 256 + 255) / 256, 256, 0, stream>>>(Wsrc1, Bt1s, 256, 256, 256, xprobe);
    k_transpose<<<(256 * 256 + 255) / 256, 256, 0, stream>>>(Wdst1, Bt1d, 256, 256, 256, xprobe);
    k_transpose<<<(192 * 256 + 255) / 256, 256, 0, stream>>>(Wsrc2, Bt2s, 256, 160, 192, xprobe);
    k_transpose<<<(192 * 256 + 255) / 256, 256, 0, stream>>>(Wdst2, Bt2d, 256, 160, 192, xprobe);
    k_transpose<<<(192 * 256 + 255) / 256, 256, 0, stream>>>(resW2, Bt2r, 256, 160, 192, xprobe);

    dim3 g256(NN / 16, 4);   // No=256 -> 4 col tiles of 64
    dim3 g160(NN / 16, 3);   // No=160 -> 3 col tiles (last partial)

    // ---- layer 0 (in=128 -> 4x64, projected residual, relu) ----
    k_gemm<<<g256, 64, 0, stream>>>(xc, Bt0s, fs, 128, 256);
    k_gemm<<<g256, 64, 0, stream>>>(xc, Bt0d, fd, 128, 256);
    k_gemm<<<g256, 64, 0, stream>>>(xc, Bt0r, res, 128, 256);
    k_aggregate<<<NN, 256, 0, stream>>>(fs, fd, res, c_attn0, c_b0, indptr, srcs, hA, DD, 1);
    hipMemsetAsync(bnsum, 0, 512 * 4, stream);   // bnsum+bnsq contiguous
    k_bn_partial<<<(NN + 127) / 128, 256, 0, stream>>>(hA, bnsum, bnsq);
    k_bn_norm<<<(int)((NF + 255) / 256), 256, 0, stream>>>(hA, bnsum, bnsq, c_g0, c_be0, hA, hbf);

    // ---- layer 1 (256 -> 4x64, identity residual = hA, relu) ----
    k_gemm<<<g256, 64, 0, stream>>>(hbf, Bt1s, fs, 256, 256);
    k_gemm<<<g256, 64, 0, stream>>>(hbf, Bt1d, fd, 256, 256);
    k_aggregate<<<NN, 256, 0, stream>>>(fs, fd, hA, c_attn1, c_b1, indptr, srcs, hB, DD, 1);
    hipMemsetAsync(bnsum, 0, 512 * 4, stream);
    k_bn_partial<<<(NN + 127) / 128, 256, 0, stream>>>(hB, bnsum, bnsq);
    k_bn_norm<<<(int)((NF + 255) / 256), 256, 0, stream>>>(hB, bnsum, bnsq, c_g1, c_be1, hB, hbf);

    // ---- layer 2 (256 -> 4x40, projected residual, no relu) ----
    k_gemm<<<g160, 64, 0, stream>>>(hbf, Bt2s, fs, 256, 160);
    k_gemm<<<g160, 64, 0, stream>>>(hbf, Bt2d, fd, 256, 160);
    k_gemm<<<g160, 64, 0, stream>>>(hbf, Bt2r, res, 256, 160);
    k_aggregate<<<NN, 256, 0, stream>>>(fs, fd, res, c_attn2, c_b2, indptr, srcs, hA, CC, 0);

    // ---- head mean + log_softmax -> float32 out ----
    k_final<<<NN / 4, 256, 0, stream>>>(hA, (float*)d_out);
}

// Round 4
// 840.278 us; speedup vs baseline: 1.3197x; 1.3197x over previous
//
#include <hip/hip_runtime.h>
#include <hip/hip_bf16.h>
#include <math.h>

#define NN 30000
#define EE 400000
#define INP 128
#define HH 4
#define DD 64
#define CC 40
#define HD 256   // H*D
#define HC 160   // H*C

typedef unsigned short ushort;
typedef __attribute__((ext_vector_type(8))) short s8v;   // 8 x bf16 bits (4 VGPRs)
typedef __attribute__((ext_vector_type(4))) float f4v;   // MFMA accumulator

// ---------------- input dtype probe ----------------
__device__ inline int detect_fp32(const ushort* xp) {
    int cnt = 0;
    for (int i = 0; i < 128; i++) {
        ushort u = xp[i];
        int e = (u >> 7) & 0xFF;
        int man = u & 0x7F;
        if (e >= 0xC0 || (e <= 0x3F && (e > 0 || man != 0))) cnt++;
    }
    return cnt >= 8;
}

__device__ inline ushort bf16_of_float(float f) {
    __hip_bfloat16 b = __float2bfloat16(f);
    return *(ushort*)&b;
}

__global__ __launch_bounds__(256) void k_cast(const void* __restrict__ in, ushort* __restrict__ out,
                                              int n, const ushort* __restrict__ xp) {
    __shared__ int isf;
    if (threadIdx.x == 0) isf = detect_fp32(xp);
    __syncthreads();
    int i = blockIdx.x * 256 + threadIdx.x;
    if (i < n) {
        out[i] = isf ? bf16_of_float(((const float*)in)[i]) : ((const ushort*)in)[i];
    }
}

// layout: b0[256] attn0[256] b1[256] attn1[256] b2[160] attn2[160] g0[256] be0[256] g1[256] be1[256]
__global__ __launch_bounds__(256) void k_cast_small(const void* b0, const void* a0, const void* b1,
                                                    const void* a1, const void* b2, const void* a2,
                                                    const void* g0, const void* be0, const void* g1,
                                                    const void* be1, ushort* __restrict__ out,
                                                    const ushort* __restrict__ xp) {
    __shared__ int isf;
    if (threadIdx.x == 0) isf = detect_fp32(xp);
    __syncthreads();
    const void* ptrs[10] = {b0, a0, b1, a1, b2, a2, g0, be0, g1, be1};
    const int sz[10] = {256, 256, 256, 256, 160, 160, 256, 256, 256, 256};
    int off = 0, t = threadIdx.x;
    for (int j = 0; j < 10; j++) {
        if (t < sz[j]) {
            out[off + t] = isf ? bf16_of_float(((const float*)ptrs[j])[t])
                               : ((const ushort*)ptrs[j])[t];
        }
        off += sz[j];
    }
}

// ---------------- CSR build ----------------

__global__ __launch_bounds__(256) void k_hist(const int* __restrict__ dst, int* __restrict__ cnt) {
    int e = blockIdx.x * 256 + threadIdx.x;
    if (e < EE) atomicAdd(&cnt[dst[e]], 1);
}

__global__ __launch_bounds__(1024) void k_scan(const int* __restrict__ cnt, int* __restrict__ indptr) {
    __shared__ int ss[1024];
    int t = threadIdx.x;
    const int CH = 30;
    int b = t * CH;
    int e2 = min(NN, b + CH);
    int s = 0;
    for (int i = b; i < e2; i++) s += cnt[i];
    ss[t] = s;
    __syncthreads();
    for (int o = 1; o < 1024; o <<= 1) {
        int v = (t >= o) ? ss[t - o] : 0;
        __syncthreads();
        ss[t] += v;
        __syncthreads();
    }
    int run = ss[t] - s;
    for (int i = b; i < e2; i++) { indptr[i] = run; run += cnt[i]; }
    if (t == 0) indptr[NN] = EE;
}

__global__ __launch_bounds__(256) void k_scatter(const int* __restrict__ src, const int* __restrict__ dst,
                                                 const int* __restrict__ indptr, int* __restrict__ pos,
                                                 int* __restrict__ srcs) {
    int e = blockIdx.x * 256 + threadIdx.x;
    if (e < EE) {
        int d = dst[e];
        int p = atomicAdd(&pos[d], 1);
        srcs[indptr[d] + p] = src[e];
    }
}

// ---------------- weight transpose ----------------

__global__ __launch_bounds__(256) void k_transpose(const void* __restrict__ W, ushort* __restrict__ Bt,
                                                   int K, int No, int Nopad,
                                                   const ushort* __restrict__ xp) {
    __shared__ int isf;
    if (threadIdx.x == 0) isf = detect_fp32(xp);
    __syncthreads();
    int i = blockIdx.x * 256 + threadIdx.x;
    if (i < Nopad * K) {
        int n = i / K, k = i - n * K;
        ushort v = 0;
        if (n < No) {
            v = isf ? bf16_of_float(((const float*)W)[k * No + n])
                    : ((const ushort*)W)[k * No + n];
        }
        Bt[i] = v;
    }
}

// ---------------- bf16 MFMA GEMM ----------------

__global__ __launch_bounds__(64) void k_gemm(const ushort* __restrict__ A, const ushort* __restrict__ Bt,
                                             float* __restrict__ Cmat, int K, int No) {
    int lane = threadIdx.x;
    int m = lane & 15, q = lane >> 4;
    int row0 = blockIdx.x * 16;
    int col0 = blockIdx.y * 64;
    f4v acc[4] = {};
    const ushort* Arow = A + (size_t)(row0 + m) * K + q * 8;
    for (int kt = 0; kt < K; kt += 32) {
        s8v a = *(const s8v*)(Arow + kt);
#pragma unroll
        for (int c = 0; c < 4; c++) {
            const ushort* Brow = Bt + (size_t)(col0 + c * 16 + m) * K + q * 8 + kt;
            s8v b = *(const s8v*)Brow;
            acc[c] = __builtin_amdgcn_mfma_f32_16x16x32_bf16(a, b, acc[c], 0, 0, 0);
        }
    }
#pragma unroll
    for (int c = 0; c < 4; c++) {
        int col = col0 + c * 16 + m;
        if (col < No) {
#pragma unroll
            for (int r = 0; r < 4; r++)
                Cmat[(size_t)(row0 + q * 4 + r) * No + col] = acc[c][r];
        }
    }
}

// ---------------- fused GATv2 edge phase ----------------
// One wave per dst node, ALL 4 heads at once. lane = 16*h + j; lane holds
// float4 = dims [4j..4j+3] of head h. One dwordx4 gather per edge per wave
// (full row, coalesced). 16-lane reduce (xor 1,2,4,8 stays in head group).
// Max-free softmax: scores are O(1) (shift-invariance => same result).

__device__ inline float4 ld4(const float* p) { return *(const float4*)p; }

__global__ __launch_bounds__(256) void k_aggregate(const float* __restrict__ fs, const float* __restrict__ fd,
                                                   const float* __restrict__ res,
                                                   const __hip_bfloat16* __restrict__ attn,
                                                   const __hip_bfloat16* __restrict__ bias,
                                                   const int* __restrict__ indptr, const int* __restrict__ srcs,
                                                   float* __restrict__ out, int Dh, int do_relu) {
    int v = blockIdx.x * 4 + (threadIdx.x >> 6);
    int lane = threadIdx.x & 63;
    int h = lane >> 4, j = lane & 15;
    int jmax = Dh >> 2;                 // 16 (D=64) or 10 (C=40)
    bool act = j < jmax;
    int F = HH * Dh;
    int off = h * Dh + 4 * j;           // element offset within row (act lanes only)
    float4 fdv = {0.f, 0.f, 0.f, 0.f}, av = {0.f, 0.f, 0.f, 0.f};
    if (act) {
        fdv = ld4(&fd[(size_t)v * F + off]);
        av.x = __bfloat162float(attn[off]);
        av.y = __bfloat162float(attn[off + 1]);
        av.z = __bfloat162float(attn[off + 2]);
        av.w = __bfloat162float(attn[off + 3]);
    }
    float l = 0.f;
    float4 acc = {0.f, 0.f, 0.f, 0.f};
    int beg = indptr[v], end = indptr[v + 1];
    int i = beg;
    for (; i + 1 < end; i += 2) {
        int u0 = srcs[i], u1 = srcs[i + 1];
        float4 f0 = {0.f,0.f,0.f,0.f}, f1 = {0.f,0.f,0.f,0.f};
        if (act) {
            f0 = ld4(&fs[(size_t)u0 * F + off]);
            f1 = ld4(&fs[(size_t)u1 * F + off]);
        }
        float tx, p0, p1;
        tx = f0.x + fdv.x; tx = tx > 0.f ? tx : 0.2f * tx; p0  = av.x * tx;
        tx = f0.y + fdv.y; tx = tx > 0.f ? tx : 0.2f * tx; p0 += av.y * tx;
        tx = f0.z + fdv.z; tx = tx > 0.f ? tx : 0.2f * tx; p0 += av.z * tx;
        tx = f0.w + fdv.w; tx = tx > 0.f ? tx : 0.2f * tx; p0 += av.w * tx;
        tx = f1.x + fdv.x; tx = tx > 0.f ? tx : 0.2f * tx; p1  = av.x * tx;
        tx = f1.y + fdv.y; tx = tx > 0.f ? tx : 0.2f * tx; p1 += av.y * tx;
        tx = f1.z + fdv.z; tx = tx > 0.f ? tx : 0.2f * tx; p1 += av.z * tx;
        tx = f1.w + fdv.w; tx = tx > 0.f ? tx : 0.2f * tx; p1 += av.w * tx;
#pragma unroll
        for (int o = 1; o < 16; o <<= 1) { p0 += __shfl_xor(p0, o, 64); p1 += __shfl_xor(p1, o, 64); }
        float w0 = __expf(p0), w1 = __expf(p1);
        l += w0 + w1;
        acc.x += w0 * f0.x + w1 * f1.x;
        acc.y += w0 * f0.y + w1 * f1.y;
        acc.z += w0 * f0.z + w1 * f1.z;
        acc.w += w0 * f0.w + w1 * f1.w;
    }
    if (i < end) {
        int u0 = srcs[i];
        float4 f0 = {0.f,0.f,0.f,0.f};
        if (act) f0 = ld4(&fs[(size_t)u0 * F + off]);
        float tx, p0;
        tx = f0.x + fdv.x; tx = tx > 0.f ? tx : 0.2f * tx; p0  = av.x * tx;
        tx = f0.y + fdv.y; tx = tx > 0.f ? tx : 0.2f * tx; p0 += av.y * tx;
        tx = f0.z + fdv.z; tx = tx > 0.f ? tx : 0.2f * tx; p0 += av.z * tx;
        tx = f0.w + fdv.w; tx = tx > 0.f ? tx : 0.2f * tx; p0 += av.w * tx;
#pragma unroll
        for (int o = 1; o < 16; o <<= 1) p0 += __shfl_xor(p0, o, 64);
        float w0 = __expf(p0);
        l += w0;
        acc.x += w0 * f0.x; acc.y += w0 * f0.y; acc.z += w0 * f0.z; acc.w += w0 * f0.w;
    }
    if (act) {
        float inv = 1.f / fmaxf(l, 1e-9f);
        size_t base = (size_t)v * F + off;
        float4 o4;
        o4.x = acc.x * inv + res[base + 0] + __bfloat162float(bias[off]);
        o4.y = acc.y * inv + res[base + 1] + __bfloat162float(bias[off + 1]);
        o4.z = acc.z * inv + res[base + 2] + __bfloat162float(bias[off + 2]);
        o4.w = acc.w * inv + res[base + 3] + __bfloat162float(bias[off + 3]);
        if (do_relu) {
            o4.x = fmaxf(o4.x, 0.f); o4.y = fmaxf(o4.y, 0.f);
            o4.z = fmaxf(o4.z, 0.f); o4.w = fmaxf(o4.w, 0.f);
        }
        *(float4*)&out[base] = o4;
    }
}

// ---------------- batchnorm ----------------

__global__ __launch_bounds__(256) void k_bn_partial(const float* __restrict__ h, float* __restrict__ sum,
                                                    float* __restrict__ sumsq) {
    int c = threadIdx.x;
    int r0 = blockIdx.x * 128;
    int r1 = min(NN, r0 + 128);
    float s = 0.f, ss = 0.f;
    for (int r = r0; r < r1; r++) {
        float vv = h[(size_t)r * HD + c];
        s += vv; ss += vv * vv;
    }
    atomicAdd(&sum[c], s);
    atomicAdd(&sumsq[c], ss);
}

__global__ __launch_bounds__(256) void k_bn_norm(const float* __restrict__ hin, const float* __restrict__ sum,
                                                 const float* __restrict__ sumsq,
                                                 const __hip_bfloat16* __restrict__ g,
                                                 const __hip_bfloat16* __restrict__ be,
                                                 float* __restrict__ hout, ushort* __restrict__ hbf) {
    int idx = blockIdx.x * 256 + threadIdx.x;
    if (idx < NN * HD) {
        int c = idx & (HD - 1);
        float mean = sum[c] * (1.0f / NN);
        float var = fmaxf(sumsq[c] * (1.0f / NN) - mean * mean, 0.f);
        float y = __bfloat162float(g[c]) * (hin[idx] - mean) * rsqrtf(var + 1e-5f) + __bfloat162float(be[c]);
        y = fmaxf(y, 0.f);
        hout[idx] = y;
        hbf[idx] = bf16_of_float(y);
    }
}

// ---------------- head-mean + log_softmax (float32 out) ----------------

__global__ __launch_bounds__(256) void k_final(const float* __restrict__ o2, float* __restrict__ out) {
    int v = blockIdx.x * 4 + (threadIdx.x >> 6);
    int lane = threadIdx.x & 63;
    bool act = lane < CC;
    float z = -1e30f;
    if (act) {
        const float* p = o2 + (size_t)v * HC;
        z = 0.25f * (p[lane] + p[CC + lane] + p[2 * CC + lane] + p[3 * CC + lane]);
    }
    float mx = z;
#pragma unroll
    for (int o = 32; o > 0; o >>= 1) mx = fmaxf(mx, __shfl_xor(mx, o, 64));
    float ex = act ? __expf(z - mx) : 0.f;
    float l = ex;
#pragma unroll
    for (int o = 32; o > 0; o >>= 1) l += __shfl_xor(l, o, 64);
    if (act) out[(size_t)v * CC + lane] = z - mx - logf(fmaxf(l, 1e-30f));
}

// ---------------- driver ----------------

static inline char* alignup(char* p) { return (char*)(((size_t)p + 255) & ~(size_t)255); }

extern "C" void kernel_launch(void* const* d_in, const int* in_sizes, int n_in,
                              void* d_out, int out_size, void* d_ws, size_t ws_size,
                              hipStream_t stream) {
    const ushort* xprobe = (const ushort*)d_in[0];
    const void* x     = d_in[0];
    const int*  src   = (const int*)d_in[1];
    const int*  dst   = (const int*)d_in[2];
    const void* Wsrc0 = d_in[3];
    const void* Wdst0 = d_in[4];
    const void* b0    = d_in[5];
    const void* attn0 = d_in[6];
    const void* resW0 = d_in[7];
    const void* Wsrc1 = d_in[8];
    const void* Wdst1 = d_in[9];
    const void* b1    = d_in[10];
    const void* attn1 = d_in[11];
    const void* Wsrc2 = d_in[12];
    const void* Wdst2 = d_in[13];
    const void* b2    = d_in[14];
    const void* attn2 = d_in[15];
    const void* resW2 = d_in[16];
    const void* g0    = d_in[17];
    const void* be0   = d_in[18];
    const void* g1    = d_in[19];
    const void* be1   = d_in[20];

    char* w = (char*)d_ws;
    const size_t NF = (size_t)NN * HD;
    float* hA  = (float*)w;  w += NF * 4;
    float* hB  = (float*)w;  w += NF * 4;
    float* fs  = (float*)w;  w += NF * 4;
    float* fd  = (float*)w;  w += NF * 4;
    float* res = (float*)w;  w += NF * 4;
    float* bnsum = (float*)w; w += 256 * 4;
    float* bnsq  = (float*)w; w += 256 * 4;
    ushort* hbf = (ushort*)w; w += NF * 2;
    ushort* xc  = (ushort*)w; w += (size_t)NN * INP * 2;
    ushort* Bt0s = (ushort*)w; w += 256 * 128 * 2;
    ushort* Bt0d = (ushort*)w; w += 256 * 128 * 2;
    ushort* Bt0r = (ushort*)w; w += 256 * 128 * 2;
    ushort* Bt1s = (ushort*)w; w += 256 * 256 * 2;
    ushort* Bt1d = (ushort*)w; w += 256 * 256 * 2;
    ushort* Bt2s = (ushort*)w; w += 192 * 256 * 2;
    ushort* Bt2d = (ushort*)w; w += 192 * 256 * 2;
    ushort* Bt2r = (ushort*)w; w += 192 * 256 * 2;
    ushort* smallv = (ushort*)w; w += 2368 * 2; w = alignup(w);
    int* indptr = (int*)w; w += (NN + 1) * 4; w = alignup(w);
    int* cnt    = (int*)w; w += NN * 4; w = alignup(w);
    int* pos    = (int*)w; w += NN * 4; w = alignup(w);
    int* srcs   = (int*)w; w += EE * 4;

    const __hip_bfloat16* c_b0    = (const __hip_bfloat16*)(smallv + 0);
    const __hip_bfloat16* c_attn0 = (const __hip_bfloat16*)(smallv + 256);
    const __hip_bfloat16* c_b1    = (const __hip_bfloat16*)(smallv + 512);
    const __hip_bfloat16* c_attn1 = (const __hip_bfloat16*)(smallv + 768);
    const __hip_bfloat16* c_b2    = (const __hip_bfloat16*)(smallv + 1024);
    const __hip_bfloat16* c_attn2 = (const __hip_bfloat16*)(smallv + 1184);
    const __hip_bfloat16* c_g0    = (const __hip_bfloat16*)(smallv + 1344);
    const __hip_bfloat16* c_be0   = (const __hip_bfloat16*)(smallv + 1600);
    const __hip_bfloat16* c_g1    = (const __hip_bfloat16*)(smallv + 1856);
    const __hip_bfloat16* c_be1   = (const __hip_bfloat16*)(smallv + 2112);

    k_cast<<<(NN * INP + 255) / 256, 256, 0, stream>>>(x, xc, NN * INP, xprobe);
    k_cast_small<<<1, 256, 0, stream>>>(b0, attn0, b1, attn1, b2, attn2, g0, be0, g1, be1,
                                        smallv, xprobe);

    hipMemsetAsync(cnt, 0, NN * 4, stream);
    hipMemsetAsync(pos, 0, NN * 4, stream);
    k_hist<<<(EE + 255) / 256, 256, 0, stream>>>(dst, cnt);
    k_scan<<<1, 1024, 0, stream>>>(cnt, indptr);
    k_scatter<<<(EE + 255) / 256, 256, 0, stream>>>(src, dst, indptr, pos, srcs);

    k_transpose<<<(256 * 128 + 255) / 256, 256, 0, stream>>>(Wsrc0, Bt0s, 128, 256, 256, xprobe);
    k_transpose<<<(256 * 128 + 255) / 256, 256, 0, stream>>>(Wdst0, Bt0d, 128, 256, 256, xprobe);
    k_transpose<<<(256 * 128 + 255) / 256, 256, 0, stream>>>(resW0, Bt0r, 128, 256, 256, xprobe);
    k_transpose<<<(256 * 256 + 255) / 256, 256, 0, stream>>>(Wsrc1, Bt1s, 256, 256, 256, xprobe);
    k_transpose<<<(256 * 256 + 255) / 256, 256, 0, stream>>>(Wdst1, Bt1d, 256, 256, 256, xprobe);
    k_transpose<<<(192 * 256 + 255) / 256, 256, 0, stream>>>(Wsrc2, Bt2s, 256, 160, 192, xprobe);
    k_transpose<<<(192 * 256 + 255) / 256, 256, 0, stream>>>(Wdst2, Bt2d, 256, 160, 192, xprobe);
    k_transpose<<<(192 * 256 + 255) / 256, 256, 0, stream>>>(resW2, Bt2r, 256, 160, 192, xprobe);

    dim3 g256(NN / 16, 4);
    dim3 g160(NN / 16, 3);

    // ---- layer 0 ----
    k_gemm<<<g256, 64, 0, stream>>>(xc, Bt0s, fs, 128, 256);
    k_gemm<<<g256, 64, 0, stream>>>(xc, Bt0d, fd, 128, 256);
    k_gemm<<<g256, 64, 0, stream>>>(xc, Bt0r, res, 128, 256);
    k_aggregate<<<NN / 4, 256, 0, stream>>>(fs, fd, res, c_attn0, c_b0, indptr, srcs, hA, DD, 1);
    hipMemsetAsync(bnsum, 0, 512 * 4, stream);
    k_bn_partial<<<(NN + 127) / 128, 256, 0, stream>>>(hA, bnsum, bnsq);
    k_bn_norm<<<(int)((NF + 255) / 256), 256, 0, stream>>>(hA, bnsum, bnsq, c_g0, c_be0, hA, hbf);

    // ---- layer 1 ----
    k_gemm<<<g256, 64, 0, stream>>>(hbf, Bt1s, fs, 256, 256);
    k_gemm<<<g256, 64, 0, stream>>>(hbf, Bt1d, fd, 256, 256);
    k_aggregate<<<NN / 4, 256, 0, stream>>>(fs, fd, hA, c_attn1, c_b1, indptr, srcs, hB, DD, 1);
    hipMemsetAsync(bnsum, 0, 512 * 4, stream);
    k_bn_partial<<<(NN + 127) / 128, 256, 0, stream>>>(hB, bnsum, bnsq);
    k_bn_norm<<<(int)((NF + 255) / 256), 256, 0, stream>>>(hB, bnsum, bnsq, c_g1, c_be1, hB, hbf);

    // ---- layer 2 ----
    k_gemm<<<g160, 64, 0, stream>>>(hbf, Bt2s, fs, 256, 160);
    k_gemm<<<g160, 64, 0, stream>>>(hbf, Bt2d, fd, 256, 160);
    k_gemm<<<g160, 64, 0, stream>>>(hbf, Bt2r, res, 256, 160);
    k_aggregate<<<NN / 4, 256, 0, stream>>>(fs, fd, res, c_attn2, c_b2, indptr, srcs, hA, CC, 0);

    k_final<<<NN / 4, 256, 0, stream>>>(hA, (float*)d_out);
}

// Round 5
// 581.154 us; speedup vs baseline: 1.9082x; 1.4459x over previous
//
#include <hip/hip_runtime.h>
#include <hip/hip_bf16.h>
#include <math.h>

#define NN 30000
#define EE 400000
#define INP 128
#define HH 4
#define DD 64
#define CC 40
#define HD 256   // H*D
#define HC 160   // H*C

typedef unsigned short ushort;
typedef __attribute__((ext_vector_type(8))) short s8v;   // 8 x bf16 bits (4 VGPRs)
typedef __attribute__((ext_vector_type(4))) float f4v;   // MFMA accumulator

// Inputs are fp32 storage holding bf16-rounded values (established r1-r4:
// bf16-read => NaN cascade; fp32-read => pass with absmax at bf16 scale).

__device__ inline ushort bf16_of_float(float f) {
    __hip_bfloat16 b = __float2bfloat16(f);
    return *(ushort*)&b;
}

// ---------------- fp32 -> bf16 cast, float4 vectorized (n % 4 == 0) ----------------
__global__ __launch_bounds__(256) void k_cast(const float* __restrict__ in, ushort* __restrict__ out,
                                              int n4) {
    int i = blockIdx.x * 256 + threadIdx.x;
    if (i < n4) {
        float4 v = ((const float4*)in)[i];
        ushort4 o;
        o.x = bf16_of_float(v.x); o.y = bf16_of_float(v.y);
        o.z = bf16_of_float(v.z); o.w = bf16_of_float(v.w);
        ((ushort4*)out)[i] = o;
    }
}

// layout: b0[256] attn0[256] b1[256] attn1[256] b2[160] attn2[160] g0[256] be0[256] g1[256] be1[256]
__global__ __launch_bounds__(256) void k_cast_small(const float* b0, const float* a0, const float* b1,
                                                    const float* a1, const float* b2, const float* a2,
                                                    const float* g0, const float* be0, const float* g1,
                                                    const float* be1, ushort* __restrict__ out) {
    const float* ptrs[10] = {b0, a0, b1, a1, b2, a2, g0, be0, g1, be1};
    const int sz[10] = {256, 256, 256, 256, 160, 160, 256, 256, 256, 256};
    int off = 0, t = threadIdx.x;
    for (int j = 0; j < 10; j++) {
        if (t < sz[j]) out[off + t] = bf16_of_float(ptrs[j][t]);
        off += sz[j];
    }
}

// ---------------- CSR build ----------------

__global__ __launch_bounds__(256) void k_hist(const int* __restrict__ dst, int* __restrict__ cnt) {
    int e = blockIdx.x * 256 + threadIdx.x;
    if (e < EE) atomicAdd(&cnt[dst[e]], 1);
}

__global__ __launch_bounds__(1024) void k_scan(const int* __restrict__ cnt, int* __restrict__ indptr) {
    __shared__ int ss[1024];
    int t = threadIdx.x;
    const int CH = 30;
    int b = t * CH;
    int e2 = min(NN, b + CH);
    int s = 0;
    for (int i = b; i < e2; i++) s += cnt[i];
    ss[t] = s;
    __syncthreads();
    for (int o = 1; o < 1024; o <<= 1) {
        int v = (t >= o) ? ss[t - o] : 0;
        __syncthreads();
        ss[t] += v;
        __syncthreads();
    }
    int run = ss[t] - s;
    for (int i = b; i < e2; i++) { indptr[i] = run; run += cnt[i]; }
    if (t == 0) indptr[NN] = EE;
}

__global__ __launch_bounds__(256) void k_scatter(const int* __restrict__ src, const int* __restrict__ dst,
                                                 const int* __restrict__ indptr, int* __restrict__ pos,
                                                 int* __restrict__ srcs) {
    int e = blockIdx.x * 256 + threadIdx.x;
    if (e < EE) {
        int d = dst[e];
        int p = atomicAdd(&pos[d], 1);
        srcs[indptr[d] + p] = src[e];
    }
}

// ---------------- weight transpose: W[K,No] fp32 -> Bt[Nopad,K] bf16, zero-pad ----------------

__global__ __launch_bounds__(256) void k_transpose(const float* __restrict__ W, ushort* __restrict__ Bt,
                                                   int K, int No, int Nopad) {
    int i = blockIdx.x * 256 + threadIdx.x;
    if (i < Nopad * K) {
        int n = i / K, k = i - n * K;
        Bt[i] = (n < No) ? bf16_of_float(W[k * No + n]) : (ushort)0;
    }
}

// ---------------- tiled bf16 MFMA GEMM, concatenated-N segments ----------------
// 128x128 tile, 4 waves (2x2 of 64x64), BK=32, LDS-staged (m93 structure).
// Bt: [Npad, K] row-major, Npad = 128*gridDim.y, segments of 256 padded cols.
// Epilogue scatters segment s (cols s*256..) to outs[s] with row stride segN.
// Fragment conventions identical to the validated r3/r4 k_gemm.

__global__ __launch_bounds__(256) void k_gemm_tiled(const ushort* __restrict__ A,
                                                    const ushort* __restrict__ Bt,
                                                    float* __restrict__ out0, float* __restrict__ out1,
                                                    float* __restrict__ out2, int K, int segN) {
    __shared__ ushort As[128 * 32];   // [row][k], 64 B rows (contiguous, m97-style)
    __shared__ ushort Bs[128 * 32];   // [col][k]
    int t = threadIdx.x;
    int wave = t >> 6, lane = t & 63;
    int m = lane & 15, q = lane >> 4;
    int row0 = blockIdx.x * 128, col0 = blockIdx.y * 128;
    int wr = (wave >> 1) << 6, wc = (wave & 1) << 6;
    f4v acc[4][4] = {};
    int c1 = t, c2 = t + 256;                 // 16B chunk ids; chunk c -> row c>>2, part c&3
    int ar1 = min(row0 + (c1 >> 2), NN - 1);  // clamp tail rows (stores are guarded)
    int ar2 = min(row0 + (c2 >> 2), NN - 1);
    const ushort* a1 = A + (size_t)ar1 * K + (c1 & 3) * 8;
    const ushort* a2 = A + (size_t)ar2 * K + (c2 & 3) * 8;
    const ushort* b1 = Bt + (size_t)(col0 + (c1 >> 2)) * K + (c1 & 3) * 8;
    const ushort* b2 = Bt + (size_t)(col0 + (c2 >> 2)) * K + (c2 & 3) * 8;

    for (int kt = 0; kt < K; kt += 32) {
        s8v va1 = *(const s8v*)(a1 + kt);
        s8v va2 = *(const s8v*)(a2 + kt);
        s8v vb1 = *(const s8v*)(b1 + kt);
        s8v vb2 = *(const s8v*)(b2 + kt);
        __syncthreads();                       // previous iter's LDS reads done
        *(s8v*)&As[c1 * 8] = va1;              // byte offset c*16
        *(s8v*)&As[c2 * 8] = va2;
        *(s8v*)&Bs[c1 * 8] = vb1;
        *(s8v*)&Bs[c2 * 8] = vb2;
        __syncthreads();
        s8v af[4], bg[4];
#pragma unroll
        for (int i = 0; i < 4; i++) af[i] = *(const s8v*)&As[(wr + i * 16 + m) * 32 + q * 8];
#pragma unroll
        for (int c = 0; c < 4; c++) bg[c] = *(const s8v*)&Bs[(wc + c * 16 + m) * 32 + q * 8];
#pragma unroll
        for (int i = 0; i < 4; i++)
#pragma unroll
            for (int c = 0; c < 4; c++)
                acc[i][c] = __builtin_amdgcn_mfma_f32_16x16x32_bf16(af[i], bg[c], acc[i][c], 0, 0, 0);
    }

#pragma unroll
    for (int c = 0; c < 4; c++) {
        int gcb = col0 + wc + c * 16;          // 16-col tile never crosses a 256 boundary
        int seg = gcb >> 8;
        int scb = (gcb & 255) + m;
        float* op = seg == 0 ? out0 : (seg == 1 ? out1 : out2);
        if (scb < segN) {
#pragma unroll
            for (int i = 0; i < 4; i++) {
                int gr0 = row0 + wr + i * 16 + q * 4;
#pragma unroll
                for (int r = 0; r < 4; r++) {
                    int gr = gr0 + r;
                    if (gr < NN) op[(size_t)gr * segN + scb] = acc[i][c][r];
                }
            }
        }
    }
}

// ---------------- fused GATv2 edge phase (unchanged from r4, passing) ----------------

__device__ inline float4 ld4(const float* p) { return *(const float4*)p; }

__global__ __launch_bounds__(256) void k_aggregate(const float* __restrict__ fs, const float* __restrict__ fd,
                                                   const float* __restrict__ res,
                                                   const __hip_bfloat16* __restrict__ attn,
                                                   const __hip_bfloat16* __restrict__ bias,
                                                   const int* __restrict__ indptr, const int* __restrict__ srcs,
                                                   float* __restrict__ out, int Dh, int do_relu) {
    int v = blockIdx.x * 4 + (threadIdx.x >> 6);
    int lane = threadIdx.x & 63;
    int h = lane >> 4, j = lane & 15;
    int jmax = Dh >> 2;
    bool act = j < jmax;
    int F = HH * Dh;
    int off = h * Dh + 4 * j;
    float4 fdv = {0.f, 0.f, 0.f, 0.f}, av = {0.f, 0.f, 0.f, 0.f};
    if (act) {
        fdv = ld4(&fd[(size_t)v * F + off]);
        av.x = __bfloat162float(attn[off]);
        av.y = __bfloat162float(attn[off + 1]);
        av.z = __bfloat162float(attn[off + 2]);
        av.w = __bfloat162float(attn[off + 3]);
    }
    float l = 0.f;
    float4 acc = {0.f, 0.f, 0.f, 0.f};
    int beg = indptr[v], end = indptr[v + 1];
    int i = beg;
    for (; i + 1 < end; i += 2) {
        int u0 = srcs[i], u1 = srcs[i + 1];
        float4 f0 = {0.f,0.f,0.f,0.f}, f1 = {0.f,0.f,0.f,0.f};
        if (act) {
            f0 = ld4(&fs[(size_t)u0 * F + off]);
            f1 = ld4(&fs[(size_t)u1 * F + off]);
        }
        float tx, p0, p1;
        tx = f0.x + fdv.x; tx = tx > 0.f ? tx : 0.2f * tx; p0  = av.x * tx;
        tx = f0.y + fdv.y; tx = tx > 0.f ? tx : 0.2f * tx; p0 += av.y * tx;
        tx = f0.z + fdv.z; tx = tx > 0.f ? tx : 0.2f * tx; p0 += av.z * tx;
        tx = f0.w + fdv.w; tx = tx > 0.f ? tx : 0.2f * tx; p0 += av.w * tx;
        tx = f1.x + fdv.x; tx = tx > 0.f ? tx : 0.2f * tx; p1  = av.x * tx;
        tx = f1.y + fdv.y; tx = tx > 0.f ? tx : 0.2f * tx; p1 += av.y * tx;
        tx = f1.z + fdv.z; tx = tx > 0.f ? tx : 0.2f * tx; p1 += av.z * tx;
        tx = f1.w + fdv.w; tx = tx > 0.f ? tx : 0.2f * tx; p1 += av.w * tx;
#pragma unroll
        for (int o = 1; o < 16; o <<= 1) { p0 += __shfl_xor(p0, o, 64); p1 += __shfl_xor(p1, o, 64); }
        float w0 = __expf(p0), w1 = __expf(p1);
        l += w0 + w1;
        acc.x += w0 * f0.x + w1 * f1.x;
        acc.y += w0 * f0.y + w1 * f1.y;
        acc.z += w0 * f0.z + w1 * f1.z;
        acc.w += w0 * f0.w + w1 * f1.w;
    }
    if (i < end) {
        int u0 = srcs[i];
        float4 f0 = {0.f,0.f,0.f,0.f};
        if (act) f0 = ld4(&fs[(size_t)u0 * F + off]);
        float tx, p0;
        tx = f0.x + fdv.x; tx = tx > 0.f ? tx : 0.2f * tx; p0  = av.x * tx;
        tx = f0.y + fdv.y; tx = tx > 0.f ? tx : 0.2f * tx; p0 += av.y * tx;
        tx = f0.z + fdv.z; tx = tx > 0.f ? tx : 0.2f * tx; p0 += av.z * tx;
        tx = f0.w + fdv.w; tx = tx > 0.f ? tx : 0.2f * tx; p0 += av.w * tx;
#pragma unroll
        for (int o = 1; o < 16; o <<= 1) p0 += __shfl_xor(p0, o, 64);
        float w0 = __expf(p0);
        l += w0;
        acc.x += w0 * f0.x; acc.y += w0 * f0.y; acc.z += w0 * f0.z; acc.w += w0 * f0.w;
    }
    if (act) {
        float inv = 1.f / fmaxf(l, 1e-9f);
        size_t base = (size_t)v * F + off;
        float4 o4;
        o4.x = acc.x * inv + res[base + 0] + __bfloat162float(bias[off]);
        o4.y = acc.y * inv + res[base + 1] + __bfloat162float(bias[off + 1]);
        o4.z = acc.z * inv + res[base + 2] + __bfloat162float(bias[off + 2]);
        o4.w = acc.w * inv + res[base + 3] + __bfloat162float(bias[off + 3]);
        if (do_relu) {
            o4.x = fmaxf(o4.x, 0.f); o4.y = fmaxf(o4.y, 0.f);
            o4.z = fmaxf(o4.z, 0.f); o4.w = fmaxf(o4.w, 0.f);
        }
        *(float4*)&out[base] = o4;
    }
}

// ---------------- batchnorm ----------------

__global__ __launch_bounds__(256) void k_bn_partial(const float* __restrict__ h, float* __restrict__ sum,
                                                    float* __restrict__ sumsq) {
    int c = threadIdx.x;
    int r0 = blockIdx.x * 128;
    int r1 = min(NN, r0 + 128);
    float s = 0.f, ss = 0.f;
    for (int r = r0; r < r1; r++) {
        float vv = h[(size_t)r * HD + c];
        s += vv; ss += vv * vv;
    }
    atomicAdd(&sum[c], s);
    atomicAdd(&sumsq[c], ss);
}

__global__ __launch_bounds__(256) void k_bn_norm(const float* __restrict__ hin, const float* __restrict__ sum,
                                                 const float* __restrict__ sumsq,
                                                 const __hip_bfloat16* __restrict__ g,
                                                 const __hip_bfloat16* __restrict__ be,
                                                 float* __restrict__ hout, ushort* __restrict__ hbf) {
    int idx = blockIdx.x * 256 + threadIdx.x;
    if (idx < NN * HD) {
        int c = idx & (HD - 1);
        float mean = sum[c] * (1.0f / NN);
        float var = fmaxf(sumsq[c] * (1.0f / NN) - mean * mean, 0.f);
        float y = __bfloat162float(g[c]) * (hin[idx] - mean) * rsqrtf(var + 1e-5f) + __bfloat162float(be[c]);
        y = fmaxf(y, 0.f);
        hout[idx] = y;
        hbf[idx] = bf16_of_float(y);
    }
}

// ---------------- head-mean + log_softmax (float32 out) ----------------

__global__ __launch_bounds__(256) void k_final(const float* __restrict__ o2, float* __restrict__ out) {
    int v = blockIdx.x * 4 + (threadIdx.x >> 6);
    int lane = threadIdx.x & 63;
    bool act = lane < CC;
    float z = -1e30f;
    if (act) {
        const float* p = o2 + (size_t)v * HC;
        z = 0.25f * (p[lane] + p[CC + lane] + p[2 * CC + lane] + p[3 * CC + lane]);
    }
    float mx = z;
#pragma unroll
    for (int o = 32; o > 0; o >>= 1) mx = fmaxf(mx, __shfl_xor(mx, o, 64));
    float ex = act ? __expf(z - mx) : 0.f;
    float l = ex;
#pragma unroll
    for (int o = 32; o > 0; o >>= 1) l += __shfl_xor(l, o, 64);
    if (act) out[(size_t)v * CC + lane] = z - mx - logf(fmaxf(l, 1e-30f));
}

// ---------------- driver ----------------

static inline char* alignup(char* p) { return (char*)(((size_t)p + 255) & ~(size_t)255); }

extern "C" void kernel_launch(void* const* d_in, const int* in_sizes, int n_in,
                              void* d_out, int out_size, void* d_ws, size_t ws_size,
                              hipStream_t stream) {
    const float* x     = (const float*)d_in[0];
    const int*  src    = (const int*)d_in[1];
    const int*  dst    = (const int*)d_in[2];
    const float* Wsrc0 = (const float*)d_in[3];
    const float* Wdst0 = (const float*)d_in[4];
    const float* b0    = (const float*)d_in[5];
    const float* attn0 = (const float*)d_in[6];
    const float* resW0 = (const float*)d_in[7];
    const float* Wsrc1 = (const float*)d_in[8];
    const float* Wdst1 = (const float*)d_in[9];
    const float* b1    = (const float*)d_in[10];
    const float* attn1 = (const float*)d_in[11];
    const float* Wsrc2 = (const float*)d_in[12];
    const float* Wdst2 = (const float*)d_in[13];
    const float* b2    = (const float*)d_in[14];
    const float* attn2 = (const float*)d_in[15];
    const float* resW2 = (const float*)d_in[16];
    const float* g0    = (const float*)d_in[17];
    const float* be0   = (const float*)d_in[18];
    const float* g1    = (const float*)d_in[19];
    const float* be1   = (const float*)d_in[20];

    char* w = (char*)d_ws;
    const size_t NF = (size_t)NN * HD;
    float* hA  = (float*)w;  w += NF * 4;
    float* hB  = (float*)w;  w += NF * 4;
    float* fs  = (float*)w;  w += NF * 4;
    float* fd  = (float*)w;  w += NF * 4;
    float* res = (float*)w;  w += NF * 4;
    float* bnsum = (float*)w; w += 256 * 4;
    float* bnsq  = (float*)w; w += 256 * 4;
    ushort* hbf = (ushort*)w; w += NF * 2;
    ushort* xc  = (ushort*)w; w += (size_t)NN * INP * 2;
    ushort* bt0 = (ushort*)w; w += 768 * 128 * 2;   // [Wsrc0|Wdst0|resW0] cols padded to 256 each
    ushort* bt1 = (ushort*)w; w += 512 * 256 * 2;   // [Wsrc1|Wdst1]
    ushort* bt2 = (ushort*)w; w += 768 * 256 * 2;   // [Wsrc2|Wdst2|resW2], 160->256 pad
    ushort* smallv = (ushort*)w; w += 2368 * 2; w = alignup(w);
    int* indptr = (int*)w; w += (NN + 1) * 4; w = alignup(w);
    int* cnt    = (int*)w; w += NN * 4; w = alignup(w);
    int* pos    = (int*)w; w += NN * 4; w = alignup(w);
    int* srcs   = (int*)w; w += EE * 4;

    const __hip_bfloat16* c_b0    = (const __hip_bfloat16*)(smallv + 0);
    const __hip_bfloat16* c_attn0 = (const __hip_bfloat16*)(smallv + 256);
    const __hip_bfloat16* c_b1    = (const __hip_bfloat16*)(smallv + 512);
    const __hip_bfloat16* c_attn1 = (const __hip_bfloat16*)(smallv + 768);
    const __hip_bfloat16* c_b2    = (const __hip_bfloat16*)(smallv + 1024);
    const __hip_bfloat16* c_attn2 = (const __hip_bfloat16*)(smallv + 1184);
    const __hip_bfloat16* c_g0    = (const __hip_bfloat16*)(smallv + 1344);
    const __hip_bfloat16* c_be0   = (const __hip_bfloat16*)(smallv + 1600);
    const __hip_bfloat16* c_g1    = (const __hip_bfloat16*)(smallv + 1856);
    const __hip_bfloat16* c_be1   = (const __hip_bfloat16*)(smallv + 2112);

    k_cast<<<(NN * INP / 4 + 255) / 256, 256, 0, stream>>>(x, xc, NN * INP / 4);
    k_cast_small<<<1, 256, 0, stream>>>(b0, attn0, b1, attn1, b2, attn2, g0, be0, g1, be1, smallv);

    hipMemsetAsync(cnt, 0, NN * 4, stream);
    hipMemsetAsync(pos, 0, NN * 4, stream);
    k_hist<<<(EE + 255) / 256, 256, 0, stream>>>(dst, cnt);
    k_scan<<<1, 1024, 0, stream>>>(cnt, indptr);
    k_scatter<<<(EE + 255) / 256, 256, 0, stream>>>(src, dst, indptr, pos, srcs);

    // concatenated weight transposes (segments of 256 padded cols)
    k_transpose<<<128, 256, 0, stream>>>(Wsrc0, bt0 +   0 * 128, 128, 256, 256);
    k_transpose<<<128, 256, 0, stream>>>(Wdst0, bt0 + 256 * 128, 128, 256, 256);
    k_transpose<<<128, 256, 0, stream>>>(resW0, bt0 + 512 * 128, 128, 256, 256);
    k_transpose<<<256, 256, 0, stream>>>(Wsrc1, bt1 +   0 * 256, 256, 256, 256);
    k_transpose<<<256, 256, 0, stream>>>(Wdst1, bt1 + 256 * 256, 256, 256, 256);
    k_transpose<<<256, 256, 0, stream>>>(Wsrc2, bt2 +   0 * 256, 256, 160, 256);
    k_transpose<<<256, 256, 0, stream>>>(Wdst2, bt2 + 256 * 256, 256, 160, 256);
    k_transpose<<<256, 256, 0, stream>>>(resW2, bt2 + 512 * 256, 256, 160, 256);

    const int MB = (NN + 127) / 128;   // 235

    // ---- layer 0: fused 3-matrix GEMM (K=128, segN=256) ----
    k_gemm_tiled<<<dim3(MB, 6), 256, 0, stream>>>(xc, bt0, fs, fd, res, 128, 256);
    k_aggregate<<<NN / 4, 256, 0, stream>>>(fs, fd, res, c_attn0, c_b0, indptr, srcs, hA, DD, 1);
    hipMemsetAsync(bnsum, 0, 512 * 4, stream);
    k_bn_partial<<<(NN + 127) / 128, 256, 0, stream>>>(hA, bnsum, bnsq);
    k_bn_norm<<<(int)((NF + 255) / 256), 256, 0, stream>>>(hA, bnsum, bnsq, c_g0, c_be0, hA, hbf);

    // ---- layer 1: fused 2-matrix GEMM (K=256), identity residual ----
    k_gemm_tiled<<<dim3(MB, 4), 256, 0, stream>>>(hbf, bt1, fs, fd, nullptr, 256, 256);
    k_aggregate<<<NN / 4, 256, 0, stream>>>(fs, fd, hA, c_attn1, c_b1, indptr, srcs, hB, DD, 1);
    hipMemsetAsync(bnsum, 0, 512 * 4, stream);
    k_bn_partial<<<(NN + 127) / 128, 256, 0, stream>>>(hB, bnsum, bnsq);
    k_bn_norm<<<(int)((NF + 255) / 256), 256, 0, stream>>>(hB, bnsum, bnsq, c_g1, c_be1, hB, hbf);

    // ---- layer 2: fused 3-matrix GEMM (K=256, segN=160) ----
    k_gemm_tiled<<<dim3(MB, 6), 256, 0, stream>>>(hbf, bt2, fs, fd, res, 256, 160);
    k_aggregate<<<NN / 4, 256, 0, stream>>>(fs, fd, res, c_attn2, c_b2, indptr, srcs, hA, CC, 0);

    k_final<<<NN / 4, 256, 0, stream>>>(hA, (float*)d_out);
}

// Round 6
// 537.032 us; speedup vs baseline: 2.0650x; 1.0822x over previous
//
#include <hip/hip_runtime.h>
#include <hip/hip_bf16.h>
#include <math.h>

#define NN 30000
#define EE 400000
#define INP 128
#define HH 4
#define DD 64
#define CC 40
#define HD 256   // H*D
#define HC 160   // H*C

typedef unsigned short ushort;
typedef __attribute__((ext_vector_type(8))) short s8v;   // 8 x bf16 bits (4 VGPRs)
typedef __attribute__((ext_vector_type(4))) float f4v;   // MFMA accumulator

// Inputs: fp32 storage holding bf16-rounded values (established r1-r4).

__device__ inline ushort bf16_of_float(float f) {
    __hip_bfloat16 b = __float2bfloat16(f);
    return *(ushort*)&b;
}
__device__ inline float b2f(ushort u) { return __uint_as_float(((unsigned)u) << 16); }

// async 16B global->LDS (dest = wave-uniform base + lane*16)
__device__ __forceinline__ void gld16(const void* g, void* l) {
    __builtin_amdgcn_global_load_lds((const __attribute__((address_space(1))) void*)g,
                                     (__attribute__((address_space(3))) void*)l, 16, 0, 0);
}

// ---------------- fp32 -> bf16 cast (x) ----------------
__global__ __launch_bounds__(256) void k_cast(const float* __restrict__ in, ushort* __restrict__ out,
                                              int n4) {
    int i = blockIdx.x * 256 + threadIdx.x;
    if (i < n4) {
        float4 v = ((const float4*)in)[i];
        ushort4 o;
        o.x = bf16_of_float(v.x); o.y = bf16_of_float(v.y);
        o.z = bf16_of_float(v.z); o.w = bf16_of_float(v.w);
        ((ushort4*)out)[i] = o;
    }
}

// layout: b0[256] attn0[256] b1[256] attn1[256] b2[160] attn2[160] g0[256] be0[256] g1[256] be1[256]
__global__ __launch_bounds__(256) void k_cast_small(const float* b0, const float* a0, const float* b1,
                                                    const float* a1, const float* b2, const float* a2,
                                                    const float* g0, const float* be0, const float* g1,
                                                    const float* be1, ushort* __restrict__ out) {
    const float* ptrs[10] = {b0, a0, b1, a1, b2, a2, g0, be0, g1, be1};
    const int sz[10] = {256, 256, 256, 256, 160, 160, 256, 256, 256, 256};
    int off = 0, t = threadIdx.x;
    for (int j = 0; j < 10; j++) {
        if (t < sz[j]) out[off + t] = bf16_of_float(ptrs[j][t]);
        off += sz[j];
    }
}

// ---------------- CSR build ----------------

__global__ __launch_bounds__(256) void k_hist(const int* __restrict__ dst, int* __restrict__ cnt) {
    int e = blockIdx.x * 256 + threadIdx.x;
    if (e < EE) atomicAdd(&cnt[dst[e]], 1);
}

__global__ __launch_bounds__(1024) void k_scan(const int* __restrict__ cnt, int* __restrict__ indptr) {
    __shared__ int ss[1024];
    int t = threadIdx.x;
    const int CH = 30;
    int b = t * CH;
    int e2 = min(NN, b + CH);
    int s = 0;
    for (int i = b; i < e2; i++) s += cnt[i];
    ss[t] = s;
    __syncthreads();
    for (int o = 1; o < 1024; o <<= 1) {
        int v = (t >= o) ? ss[t - o] : 0;
        __syncthreads();
        ss[t] += v;
        __syncthreads();
    }
    int run = ss[t] - s;
    for (int i = b; i < e2; i++) { indptr[i] = run; run += cnt[i]; }
    if (t == 0) indptr[NN] = EE;
}

__global__ __launch_bounds__(256) void k_scatter(const int* __restrict__ src, const int* __restrict__ dst,
                                                 const int* __restrict__ indptr, int* __restrict__ pos,
                                                 int* __restrict__ srcs) {
    int e = blockIdx.x * 256 + threadIdx.x;
    if (e < EE) {
        int d = dst[e];
        int p = atomicAdd(&pos[d], 1);
        srcs[indptr[d] + p] = src[e];
    }
}

// ---------------- all 8 weight transposes in one launch ----------------
// W[K,No] fp32 -> Bt[Npad,K] bf16 (zero-pad cols to 256)

__global__ __launch_bounds__(256) void k_transpose_all(
        const float* W0, const float* W1, const float* W2, const float* W3,
        const float* W4, const float* W5, const float* W6, const float* W7,
        ushort* bt0, ushort* bt1, ushort* bt2) {
    // seg sizes: 3 x 256*128, 5 x 256*256
    const int c0 = 32768, c3 = 98304, seg256 = 65536;
    int g = blockIdx.x * 256 + threadIdx.x;       // < 425984
    const float* Ws[8] = {W0, W1, W2, W3, W4, W5, W6, W7};
    int seg, local, K, No;
    ushort* dst;
    if (g < c3) {
        seg = g / c0; local = g - seg * c0; K = 128; No = 256;
        dst = bt0 + seg * c0;
    } else {
        int gg = g - c3;
        int s5 = gg / seg256; local = gg - s5 * seg256; seg = 3 + s5; K = 256;
        No = (seg >= 5) ? 160 : 256;
        dst = (seg < 5) ? bt1 + (seg - 3) * seg256 : bt2 + (seg - 5) * seg256;
    }
    int n = (K == 128) ? (local >> 7) : (local >> 8);
    int k = local & (K - 1);
    dst[local] = (n < No) ? bf16_of_float(Ws[seg][k * No + n]) : (ushort)0;
}

// ---------------- tiled bf16 MFMA GEMM, concatenated-N segments ----------------
// 128x128 tile, 4 waves, BK=32, async global_load_lds staging (m97-style).
// Epilogue: segments 0,1 -> bf16 (fs/fd); segment 2 -> fp32 (res).

__global__ __launch_bounds__(256) void k_gemm_tiled(const ushort* __restrict__ A,
                                                    const ushort* __restrict__ Bt,
                                                    ushort* __restrict__ out0, ushort* __restrict__ out1,
                                                    float* __restrict__ out2, int K, int segN) {
    __shared__ ushort As[128 * 32];   // chunk c (16B) at byte c*16; row = c>>2, kpart = c&3
    __shared__ ushort Bs[128 * 32];
    int t = threadIdx.x;
    int wave = t >> 6, lane = t & 63;
    int m = lane & 15, q = lane >> 4;
    int row0 = blockIdx.x * 128, col0 = blockIdx.y * 128;
    int wr = (wave >> 1) << 6, wc = (wave & 1) << 6;
    f4v acc[4][4] = {};
    int c1 = t, c2 = t + 256;
    int ar1 = min(row0 + (c1 >> 2), NN - 1);
    int ar2 = min(row0 + (c2 >> 2), NN - 1);
    const ushort* a1 = A + (size_t)ar1 * K + (c1 & 3) * 8;
    const ushort* a2 = A + (size_t)ar2 * K + (c2 & 3) * 8;
    const ushort* b1 = Bt + (size_t)(col0 + (c1 >> 2)) * K + (c1 & 3) * 8;
    const ushort* b2 = Bt + (size_t)(col0 + (c2 >> 2)) * K + (c2 & 3) * 8;
    int wbase = wave << 10;                       // wave-uniform LDS byte base
    char* AsB = (char*)As;
    char* BsB = (char*)Bs;

    for (int kt = 0; kt < K; kt += 32) {
        __syncthreads();                          // prior iter's LDS reads complete
        gld16(a1 + kt, AsB + wbase);
        gld16(a2 + kt, AsB + 4096 + wbase);
        gld16(b1 + kt, BsB + wbase);
        gld16(b2 + kt, BsB + 4096 + wbase);
        __syncthreads();                          // drains vmcnt (async LDS writes)
        s8v af[4], bg[4];
#pragma unroll
        for (int i = 0; i < 4; i++) af[i] = *(const s8v*)&As[(wr + i * 16 + m) * 32 + q * 8];
#pragma unroll
        for (int c = 0; c < 4; c++) bg[c] = *(const s8v*)&Bs[(wc + c * 16 + m) * 32 + q * 8];
#pragma unroll
        for (int i = 0; i < 4; i++)
#pragma unroll
            for (int c = 0; c < 4; c++)
                acc[i][c] = __builtin_amdgcn_mfma_f32_16x16x32_bf16(af[i], bg[c], acc[i][c], 0, 0, 0);
    }

#pragma unroll
    for (int c = 0; c < 4; c++) {
        int gcb = col0 + wc + c * 16;             // 16-col tile never crosses a 256 boundary
        int seg = gcb >> 8;
        int scb = (gcb & 255) + m;
        if (scb < segN) {
            if (seg < 2) {
                ushort* op = seg == 0 ? out0 : out1;
#pragma unroll
                for (int i = 0; i < 4; i++) {
                    int gr0 = row0 + wr + i * 16 + q * 4;
#pragma unroll
                    for (int r = 0; r < 4; r++) {
                        int gr = gr0 + r;
                        if (gr < NN) op[(size_t)gr * segN + scb] = bf16_of_float(acc[i][c][r]);
                    }
                }
            } else {
#pragma unroll
                for (int i = 0; i < 4; i++) {
                    int gr0 = row0 + wr + i * 16 + q * 4;
#pragma unroll
                    for (int r = 0; r < 4; r++) {
                        int gr = gr0 + r;
                        if (gr < NN) out2[(size_t)gr * segN + scb] = acc[i][c][r];
                    }
                }
            }
        }
    }
}

// ---------------- fused GATv2 edge phase ----------------
// One wave per dst node, all 4 heads. lane=16h+j holds dims [4j..4j+3] of head h.
// fs/fd are bf16 (halved gather bytes); res fp32; out fp32.
// 4-edge unroll = 4 independent gather chains in flight.

__global__ __launch_bounds__(256) void k_aggregate(const ushort* __restrict__ fs, const ushort* __restrict__ fd,
                                                   const float* __restrict__ res,
                                                   const ushort* __restrict__ attn,
                                                   const ushort* __restrict__ bias,
                                                   const int* __restrict__ indptr, const int* __restrict__ srcs,
                                                   float* __restrict__ out, int Dh, int do_relu) {
    int v = blockIdx.x * 4 + (threadIdx.x >> 6);
    int lane = threadIdx.x & 63;
    int h = lane >> 4, j = lane & 15;
    int jmax = Dh >> 2;
    bool act = j < jmax;
    int F = HH * Dh;
    int off = h * Dh + 4 * j;
    float4 fdv = {0.f,0.f,0.f,0.f}, av = {0.f,0.f,0.f,0.f};
    if (act) {
        ushort4 rd = *(const ushort4*)&fd[(size_t)v * F + off];
        fdv.x = b2f(rd.x); fdv.y = b2f(rd.y); fdv.z = b2f(rd.z); fdv.w = b2f(rd.w);
        ushort4 ra = *(const ushort4*)&attn[off];
        av.x = b2f(ra.x); av.y = b2f(ra.y); av.z = b2f(ra.z); av.w = b2f(ra.w);
    }
    auto ldrow = [&](int u) -> float4 {
        float4 f = {0.f,0.f,0.f,0.f};
        if (act) {
            ushort4 r = *(const ushort4*)&fs[(size_t)u * F + off];
            f.x = b2f(r.x); f.y = b2f(r.y); f.z = b2f(r.z); f.w = b2f(r.w);
        }
        return f;
    };
    auto dotlr = [&](const float4& f) -> float {
        float tx, p;
        tx = f.x + fdv.x; tx = tx > 0.f ? tx : 0.2f * tx; p  = av.x * tx;
        tx = f.y + fdv.y; tx = tx > 0.f ? tx : 0.2f * tx; p += av.y * tx;
        tx = f.z + fdv.z; tx = tx > 0.f ? tx : 0.2f * tx; p += av.z * tx;
        tx = f.w + fdv.w; tx = tx > 0.f ? tx : 0.2f * tx; p += av.w * tx;
        return p;
    };
    float l = 0.f;
    float4 acc = {0.f,0.f,0.f,0.f};
    int beg = indptr[v], end = indptr[v + 1];
    int i = beg;
    for (; i + 3 < end; i += 4) {
        int u0 = srcs[i], u1 = srcs[i+1], u2 = srcs[i+2], u3 = srcs[i+3];
        float4 f0 = ldrow(u0), f1 = ldrow(u1), f2 = ldrow(u2), f3 = ldrow(u3);
        float p0 = dotlr(f0), p1 = dotlr(f1), p2 = dotlr(f2), p3 = dotlr(f3);
#pragma unroll
        for (int o = 1; o < 16; o <<= 1) {
            p0 += __shfl_xor(p0, o, 64); p1 += __shfl_xor(p1, o, 64);
            p2 += __shfl_xor(p2, o, 64); p3 += __shfl_xor(p3, o, 64);
        }
        float w0 = __expf(p0), w1 = __expf(p1), w2 = __expf(p2), w3 = __expf(p3);
        l += (w0 + w1) + (w2 + w3);
        acc.x += (w0*f0.x + w1*f1.x) + (w2*f2.x + w3*f3.x);
        acc.y += (w0*f0.y + w1*f1.y) + (w2*f2.y + w3*f3.y);
        acc.z += (w0*f0.z + w1*f1.z) + (w2*f2.z + w3*f3.z);
        acc.w += (w0*f0.w + w1*f1.w) + (w2*f2.w + w3*f3.w);
    }
    for (; i < end; i++) {
        float4 f0 = ldrow(srcs[i]);
        float p0 = dotlr(f0);
#pragma unroll
        for (int o = 1; o < 16; o <<= 1) p0 += __shfl_xor(p0, o, 64);
        float w0 = __expf(p0);
        l += w0;
        acc.x += w0*f0.x; acc.y += w0*f0.y; acc.z += w0*f0.z; acc.w += w0*f0.w;
    }
    if (act) {
        float inv = 1.f / fmaxf(l, 1e-9f);
        size_t base = (size_t)v * F + off;
        const float4 r4 = *(const float4*)&res[base];
        float4 o4;
        o4.x = acc.x * inv + r4.x + b2f(bias[off]);
        o4.y = acc.y * inv + r4.y + b2f(bias[off + 1]);
        o4.z = acc.z * inv + r4.z + b2f(bias[off + 2]);
        o4.w = acc.w * inv + r4.w + b2f(bias[off + 3]);
        if (do_relu) {
            o4.x = fmaxf(o4.x, 0.f); o4.y = fmaxf(o4.y, 0.f);
            o4.z = fmaxf(o4.z, 0.f); o4.w = fmaxf(o4.w, 0.f);
        }
        *(float4*)&out[base] = o4;
    }
}

// ---------------- batchnorm ----------------

__global__ __launch_bounds__(256) void k_bn_partial(const float* __restrict__ h, float* __restrict__ sum,
                                                    float* __restrict__ sumsq) {
    int c = threadIdx.x;
    int r0 = blockIdx.x * 128;
    int r1 = min(NN, r0 + 128);
    float s = 0.f, ss = 0.f;
    for (int r = r0; r < r1; r++) {
        float vv = h[(size_t)r * HD + c];
        s += vv; ss += vv * vv;
    }
    atomicAdd(&sum[c], s);
    atomicAdd(&sumsq[c], ss);
}

__global__ __launch_bounds__(256) void k_bn_norm(const float* __restrict__ hin, const float* __restrict__ sum,
                                                 const float* __restrict__ sumsq,
                                                 const ushort* __restrict__ g,
                                                 const ushort* __restrict__ be,
                                                 float* __restrict__ hout, ushort* __restrict__ hbf) {
    int idx = blockIdx.x * 256 + threadIdx.x;
    if (idx < NN * HD) {
        int c = idx & (HD - 1);
        float mean = sum[c] * (1.0f / NN);
        float var = fmaxf(sumsq[c] * (1.0f / NN) - mean * mean, 0.f);
        float y = b2f(g[c]) * (hin[idx] - mean) * rsqrtf(var + 1e-5f) + b2f(be[c]);
        y = fmaxf(y, 0.f);
        if (hout) hout[idx] = y;
        hbf[idx] = bf16_of_float(y);
    }
}

// ---------------- head-mean + log_softmax (float32 out) ----------------

__global__ __launch_bounds__(256) void k_final(const float* __restrict__ o2, float* __restrict__ out) {
    int v = blockIdx.x * 4 + (threadIdx.x >> 6);
    int lane = threadIdx.x & 63;
    bool act = lane < CC;
    float z = -1e30f;
    if (act) {
        const float* p = o2 + (size_t)v * HC;
        z = 0.25f * (p[lane] + p[CC + lane] + p[2 * CC + lane] + p[3 * CC + lane]);
    }
    float mx = z;
#pragma unroll
    for (int o = 32; o > 0; o >>= 1) mx = fmaxf(mx, __shfl_xor(mx, o, 64));
    float ex = act ? __expf(z - mx) : 0.f;
    float l = ex;
#pragma unroll
    for (int o = 32; o > 0; o >>= 1) l += __shfl_xor(l, o, 64);
    if (act) out[(size_t)v * CC + lane] = z - mx - logf(fmaxf(l, 1e-30f));
}

// ---------------- driver ----------------

static inline char* alignup(char* p) { return (char*)(((size_t)p + 255) & ~(size_t)255); }

extern "C" void kernel_launch(void* const* d_in, const int* in_sizes, int n_in,
                              void* d_out, int out_size, void* d_ws, size_t ws_size,
                              hipStream_t stream) {
    const float* x     = (const float*)d_in[0];
    const int*  src    = (const int*)d_in[1];
    const int*  dst    = (const int*)d_in[2];
    const float* Wsrc0 = (const float*)d_in[3];
    const float* Wdst0 = (const float*)d_in[4];
    const float* b0    = (const float*)d_in[5];
    const float* attn0 = (const float*)d_in[6];
    const float* resW0 = (const float*)d_in[7];
    const float* Wsrc1 = (const float*)d_in[8];
    const float* Wdst1 = (const float*)d_in[9];
    const float* b1    = (const float*)d_in[10];
    const float* attn1 = (const float*)d_in[11];
    const float* Wsrc2 = (const float*)d_in[12];
    const float* Wdst2 = (const float*)d_in[13];
    const float* b2    = (const float*)d_in[14];
    const float* attn2 = (const float*)d_in[15];
    const float* resW2 = (const float*)d_in[16];
    const float* g0    = (const float*)d_in[17];
    const float* be0   = (const float*)d_in[18];
    const float* g1    = (const float*)d_in[19];
    const float* be1   = (const float*)d_in[20];

    char* w = (char*)d_ws;
    const size_t NF = (size_t)NN * HD;
    float* hA  = (float*)w;  w += NF * 4;
    float* hB  = (float*)w;  w += NF * 4;
    float* res = (float*)w;  w += NF * 4;
    ushort* fsb = (ushort*)w; w += NF * 2;
    ushort* fdb = (ushort*)w; w += NF * 2;
    float* bnsum = (float*)w; w += 256 * 4;
    float* bnsq  = (float*)w; w += 256 * 4;
    ushort* hbf = (ushort*)w; w += NF * 2;
    ushort* xc  = (ushort*)w; w += (size_t)NN * INP * 2;
    ushort* bt0 = (ushort*)w; w += 768 * 128 * 2;   // [Wsrc0|Wdst0|resW0]
    ushort* bt1 = (ushort*)w; w += 512 * 256 * 2;   // [Wsrc1|Wdst1]
    ushort* bt2 = (ushort*)w; w += 768 * 256 * 2;   // [Wsrc2|Wdst2|resW2]
    ushort* smallv = (ushort*)w; w += 2368 * 2; w = alignup(w);
    int* indptr = (int*)w; w += (NN + 1) * 4; w = alignup(w);
    int* cnt    = (int*)w; w += NN * 4;             // cnt and pos contiguous: one memset
    int* pos    = (int*)w; w += NN * 4; w = alignup(w);
    int* srcs   = (int*)w; w += EE * 4;

    const ushort* c_b0    = smallv + 0;
    const ushort* c_attn0 = smallv + 256;
    const ushort* c_b1    = smallv + 512;
    const ushort* c_attn1 = smallv + 768;
    const ushort* c_b2    = smallv + 1024;
    const ushort* c_attn2 = smallv + 1184;
    const ushort* c_g0    = smallv + 1344;
    const ushort* c_be0   = smallv + 1600;
    const ushort* c_g1    = smallv + 1856;
    const ushort* c_be1   = smallv + 2112;

    k_cast<<<(NN * INP / 4 + 255) / 256, 256, 0, stream>>>(x, xc, NN * INP / 4);
    k_cast_small<<<1, 256, 0, stream>>>(b0, attn0, b1, attn1, b2, attn2, g0, be0, g1, be1, smallv);

    hipMemsetAsync(cnt, 0, 2 * NN * 4, stream);
    k_hist<<<(EE + 255) / 256, 256, 0, stream>>>(dst, cnt);
    k_scan<<<1, 1024, 0, stream>>>(cnt, indptr);
    k_scatter<<<(EE + 255) / 256, 256, 0, stream>>>(src, dst, indptr, pos, srcs);

    k_transpose_all<<<1664, 256, 0, stream>>>(Wsrc0, Wdst0, resW0, Wsrc1, Wdst1,
                                              Wsrc2, Wdst2, resW2, bt0, bt1, bt2);

    const int MB = (NN + 127) / 128;   // 235

    // ---- layer 0: fused 3-matrix GEMM (K=128) ----
    k_gemm_tiled<<<dim3(MB, 6), 256, 0, stream>>>(xc, bt0, fsb, fdb, res, 128, 256);
    k_aggregate<<<NN / 4, 256, 0, stream>>>(fsb, fdb, res, c_attn0, c_b0, indptr, srcs, hA, DD, 1);
    hipMemsetAsync(bnsum, 0, 512 * 4, stream);
    k_bn_partial<<<(NN + 127) / 128, 256, 0, stream>>>(hA, bnsum, bnsq);
    k_bn_norm<<<(int)((NF + 255) / 256), 256, 0, stream>>>(hA, bnsum, bnsq, c_g0, c_be0, hA, hbf);

    // ---- layer 1: fused 2-matrix GEMM (K=256), identity residual = hA ----
    k_gemm_tiled<<<dim3(MB, 4), 256, 0, stream>>>(hbf, bt1, fsb, fdb, nullptr, 256, 256);
    k_aggregate<<<NN / 4, 256, 0, stream>>>(fsb, fdb, hA, c_attn1, c_b1, indptr, srcs, hB, DD, 1);
    hipMemsetAsync(bnsum, 0, 512 * 4, stream);
    k_bn_partial<<<(NN + 127) / 128, 256, 0, stream>>>(hB, bnsum, bnsq);
    k_bn_norm<<<(int)((NF + 255) / 256), 256, 0, stream>>>(hB, bnsum, bnsq, c_g1, c_be1, nullptr, hbf);

    // ---- layer 2: fused 3-matrix GEMM (K=256, segN=160) ----
    k_gemm_tiled<<<dim3(MB, 6), 256, 0, stream>>>(hbf, bt2, fsb, fdb, res, 256, 160);
    k_aggregate<<<NN / 4, 256, 0, stream>>>(fsb, fdb, res, c_attn2, c_b2, indptr, srcs, hA, CC, 0);

    k_final<<<NN / 4, 256, 0, stream>>>(hA, (float*)d_out);
}

// Round 7
// 500.162 us; speedup vs baseline: 2.2172x; 1.0737x over previous
//
#include <hip/hip_runtime.h>
#include <hip/hip_bf16.h>
#include <math.h>

#define NN 30000
#define EE 400000
#define INP 128
#define HH 4
#define DD 64
#define CC 40
#define HD 256   // H*D
#define HC 160   // H*C

typedef unsigned short ushort;
typedef __attribute__((ext_vector_type(8))) short s8v;   // 8 x bf16 bits (4 VGPRs)
typedef __attribute__((ext_vector_type(4))) float f4v;   // MFMA accumulator

// Inputs: fp32 storage holding bf16-rounded values (established r1-r4).

__device__ inline ushort bf16_of_float(float f) {
    __hip_bfloat16 b = __float2bfloat16(f);
    return *(ushort*)&b;
}
__device__ inline float b2f(ushort u) { return __uint_as_float(((unsigned)u) << 16); }

// async 16B global->LDS (dest = wave-uniform base + lane*16)
__device__ __forceinline__ void gld16(const void* g, void* l) {
    __builtin_amdgcn_global_load_lds((const __attribute__((address_space(1))) void*)g,
                                     (__attribute__((address_space(3))) void*)l, 16, 0, 0);
}

// 16-lane (DPP row) rotate-reduction: every lane gets the row sum. VALU-only.
__device__ __forceinline__ float rowsum16(float x) {
    int t;
    t = __builtin_amdgcn_update_dpp(0, __float_as_int(x), 0x128, 0xF, 0xF, false); // row_ror:8
    x += __int_as_float(t);
    t = __builtin_amdgcn_update_dpp(0, __float_as_int(x), 0x124, 0xF, 0xF, false); // row_ror:4
    x += __int_as_float(t);
    t = __builtin_amdgcn_update_dpp(0, __float_as_int(x), 0x122, 0xF, 0xF, false); // row_ror:2
    x += __int_as_float(t);
    t = __builtin_amdgcn_update_dpp(0, __float_as_int(x), 0x121, 0xF, 0xF, false); // row_ror:1
    x += __int_as_float(t);
    return x;
}

// ---------------- fp32 -> bf16 cast: x (blocks 0..nb-1) + small vectors (last block) ----------------
__global__ __launch_bounds__(256) void k_cast_all(const float* __restrict__ in, ushort* __restrict__ out,
                                                  int n4,
                                                  const float* b0, const float* a0, const float* b1,
                                                  const float* a1, const float* b2, const float* a2,
                                                  const float* g0, const float* be0, const float* g1,
                                                  const float* be1, ushort* __restrict__ smallv) {
    int nb = gridDim.x - 1;
    if ((int)blockIdx.x < nb) {
        int i = blockIdx.x * 256 + threadIdx.x;
        if (i < n4) {
            float4 v = ((const float4*)in)[i];
            ushort4 o;
            o.x = bf16_of_float(v.x); o.y = bf16_of_float(v.y);
            o.z = bf16_of_float(v.z); o.w = bf16_of_float(v.w);
            ((ushort4*)out)[i] = o;
        }
    } else {
        const float* ptrs[10] = {b0, a0, b1, a1, b2, a2, g0, be0, g1, be1};
        const int sz[10] = {256, 256, 256, 256, 160, 160, 256, 256, 256, 256};
        int off = 0, t = threadIdx.x;
        for (int j = 0; j < 10; j++) {
            if (t < sz[j]) smallv[off + t] = bf16_of_float(ptrs[j][t]);
            off += sz[j];
        }
    }
}

// ---------------- CSR build ----------------

__global__ __launch_bounds__(256) void k_hist(const int* __restrict__ dst, int* __restrict__ cnt) {
    int e = blockIdx.x * 256 + threadIdx.x;
    if (e < EE) atomicAdd(&cnt[dst[e]], 1);
}

__global__ __launch_bounds__(1024) void k_scan(const int* __restrict__ cnt, int* __restrict__ indptr) {
    __shared__ int ss[1024];
    int t = threadIdx.x;
    const int CH = 30;
    int b = t * CH;
    int e2 = min(NN, b + CH);
    int s = 0;
    for (int i = b; i < e2; i++) s += cnt[i];
    ss[t] = s;
    __syncthreads();
    for (int o = 1; o < 1024; o <<= 1) {
        int v = (t >= o) ? ss[t - o] : 0;
        __syncthreads();
        ss[t] += v;
        __syncthreads();
    }
    int run = ss[t] - s;
    for (int i = b; i < e2; i++) { indptr[i] = run; run += cnt[i]; }
    if (t == 0) indptr[NN] = EE;
}

__global__ __launch_bounds__(256) void k_scatter(const int* __restrict__ src, const int* __restrict__ dst,
                                                 const int* __restrict__ indptr, int* __restrict__ pos,
                                                 int* __restrict__ srcs) {
    int e = blockIdx.x * 256 + threadIdx.x;
    if (e < EE) {
        int d = dst[e];
        int p = atomicAdd(&pos[d], 1);
        srcs[indptr[d] + p] = src[e];
    }
}

// ---------------- all 8 weight transposes in one launch ----------------

__global__ __launch_bounds__(256) void k_transpose_all(
        const float* W0, const float* W1, const float* W2, const float* W3,
        const float* W4, const float* W5, const float* W6, const float* W7,
        ushort* bt0, ushort* bt1, ushort* bt2) {
    const int c0 = 32768, c3 = 98304, seg256 = 65536;
    int g = blockIdx.x * 256 + threadIdx.x;       // < 425984
    const float* Ws[8] = {W0, W1, W2, W3, W4, W5, W6, W7};
    int seg, local, K, No;
    ushort* dst;
    if (g < c3) {
        seg = g / c0; local = g - seg * c0; K = 128; No = 256;
        dst = bt0 + seg * c0;
    } else {
        int gg = g - c3;
        int s5 = gg / seg256; local = gg - s5 * seg256; seg = 3 + s5; K = 256;
        No = (seg >= 5) ? 160 : 256;
        dst = (seg < 5) ? bt1 + (seg - 3) * seg256 : bt2 + (seg - 5) * seg256;
    }
    int n = (K == 128) ? (local >> 7) : (local >> 8);
    int k = local & (K - 1);
    dst[local] = (n < No) ? bf16_of_float(Ws[seg][k * No + n]) : (ushort)0;
}

// ---------------- tiled bf16 MFMA GEMM, compile-time K / segN ----------------
// 128x128 tile, 4 waves, BK=32, async global_load_lds staging.
// Segments 0,1 -> bf16 (fs/fd); segment 2 -> fp32 (res).

template<int K, int SEGN>
__global__ __launch_bounds__(256) void k_gemm_tiled(const ushort* __restrict__ A,
                                                    const ushort* __restrict__ Bt,
                                                    ushort* __restrict__ out0, ushort* __restrict__ out1,
                                                    float* __restrict__ out2) {
    __shared__ ushort As[128 * 32];   // chunk c (16B) at byte c*16; row = c>>2, kpart = c&3
    __shared__ ushort Bs[128 * 32];
    int t = threadIdx.x;
    int wave = t >> 6, lane = t & 63;
    int m = lane & 15, q = lane >> 4;
    int row0 = blockIdx.x * 128, col0 = blockIdx.y * 128;
    int wr = (wave >> 1) << 6, wc = (wave & 1) << 6;
    f4v acc[4][4] = {};
    int c1 = t, c2 = t + 256;
    int ar1 = min(row0 + (c1 >> 2), NN - 1);
    int ar2 = min(row0 + (c2 >> 2), NN - 1);
    const ushort* a1 = A + (size_t)ar1 * K + (c1 & 3) * 8;
    const ushort* a2 = A + (size_t)ar2 * K + (c2 & 3) * 8;
    const ushort* b1 = Bt + (size_t)(col0 + (c1 >> 2)) * K + (c1 & 3) * 8;
    const ushort* b2 = Bt + (size_t)(col0 + (c2 >> 2)) * K + (c2 & 3) * 8;
    int wbase = wave << 10;                       // wave-uniform LDS byte base
    char* AsB = (char*)As;
    char* BsB = (char*)Bs;

#pragma unroll
    for (int kt = 0; kt < K; kt += 32) {
        __syncthreads();                          // prior iter's LDS reads complete
        gld16(a1 + kt, AsB + wbase);
        gld16(a2 + kt, AsB + 4096 + wbase);
        gld16(b1 + kt, BsB + wbase);
        gld16(b2 + kt, BsB + 4096 + wbase);
        __syncthreads();                          // drains vmcnt (async LDS writes)
        s8v af[4], bg[4];
#pragma unroll
        for (int i = 0; i < 4; i++) af[i] = *(const s8v*)&As[(wr + i * 16 + m) * 32 + q * 8];
#pragma unroll
        for (int c = 0; c < 4; c++) bg[c] = *(const s8v*)&Bs[(wc + c * 16 + m) * 32 + q * 8];
#pragma unroll
        for (int i = 0; i < 4; i++)
#pragma unroll
            for (int c = 0; c < 4; c++)
                acc[i][c] = __builtin_amdgcn_mfma_f32_16x16x32_bf16(af[i], bg[c], acc[i][c], 0, 0, 0);
    }

#pragma unroll
    for (int c = 0; c < 4; c++) {
        int gcb = col0 + wc + c * 16;             // 16-col tile never crosses a 256 boundary
        int seg = gcb >> 8;
        int scb = (gcb & 255) + m;
        if (scb < SEGN) {
            if (seg < 2) {
                ushort* op = seg == 0 ? out0 : out1;
#pragma unroll
                for (int i = 0; i < 4; i++) {
                    int gr0 = row0 + wr + i * 16 + q * 4;
#pragma unroll
                    for (int r = 0; r < 4; r++) {
                        int gr = gr0 + r;
                        if (gr < NN) op[(size_t)gr * SEGN + scb] = bf16_of_float(acc[i][c][r]);
                    }
                }
            } else {
#pragma unroll
                for (int i = 0; i < 4; i++) {
                    int gr0 = row0 + wr + i * 16 + q * 4;
#pragma unroll
                    for (int r = 0; r < 4; r++) {
                        int gr = gr0 + r;
                        if (gr < NN) out2[(size_t)gr * SEGN + scb] = acc[i][c][r];
                    }
                }
            }
        }
    }
}

// ---------------- fused GATv2 edge phase, compile-time Dh ----------------
// One wave per dst node, all 4 heads. lane=16h+j holds dims [4j..4j+3] of head h.
// fs/fd bf16; res fp32; out fp32. 4-edge unroll; DPP row reduce.

template<int DH>
__global__ __launch_bounds__(256) void k_aggregate(const ushort* __restrict__ fs, const ushort* __restrict__ fd,
                                                   const float* __restrict__ res,
                                                   const ushort* __restrict__ attn,
                                                   const ushort* __restrict__ bias,
                                                   const int* __restrict__ indptr, const int* __restrict__ srcs,
                                                   float* __restrict__ out, int do_relu) {
    constexpr int F = HH * DH;
    constexpr int JMAX = DH >> 2;
    int v = blockIdx.x * 4 + (threadIdx.x >> 6);
    int lane = threadIdx.x & 63;
    int h = lane >> 4, j = lane & 15;
    bool act = j < JMAX;
    int off = h * DH + 4 * j;
    float4 fdv = {0.f,0.f,0.f,0.f}, av = {0.f,0.f,0.f,0.f};
    if (act) {
        ushort4 rd = *(const ushort4*)&fd[(size_t)v * F + off];
        fdv.x = b2f(rd.x); fdv.y = b2f(rd.y); fdv.z = b2f(rd.z); fdv.w = b2f(rd.w);
        ushort4 ra = *(const ushort4*)&attn[off];
        av.x = b2f(ra.x); av.y = b2f(ra.y); av.z = b2f(ra.z); av.w = b2f(ra.w);
    }
    auto ldrow = [&](int u) -> float4 {
        float4 f = {0.f,0.f,0.f,0.f};
        if (act) {
            ushort4 r = *(const ushort4*)&fs[(size_t)u * F + off];
            f.x = b2f(r.x); f.y = b2f(r.y); f.z = b2f(r.z); f.w = b2f(r.w);
        }
        return f;
    };
    auto dotlr = [&](const float4& f) -> float {
        float tx, p;
        tx = f.x + fdv.x; tx = tx > 0.f ? tx : 0.2f * tx; p  = av.x * tx;
        tx = f.y + fdv.y; tx = tx > 0.f ? tx : 0.2f * tx; p += av.y * tx;
        tx = f.z + fdv.z; tx = tx > 0.f ? tx : 0.2f * tx; p += av.z * tx;
        tx = f.w + fdv.w; tx = tx > 0.f ? tx : 0.2f * tx; p += av.w * tx;
        return p;
    };
    float l = 0.f;
    float4 acc = {0.f,0.f,0.f,0.f};
    int beg = indptr[v], end = indptr[v + 1];
    int i = beg;
    for (; i + 3 < end; i += 4) {
        int u0 = srcs[i], u1 = srcs[i+1], u2 = srcs[i+2], u3 = srcs[i+3];
        float4 f0 = ldrow(u0), f1 = ldrow(u1), f2 = ldrow(u2), f3 = ldrow(u3);
        float p0 = rowsum16(dotlr(f0));
        float p1 = rowsum16(dotlr(f1));
        float p2 = rowsum16(dotlr(f2));
        float p3 = rowsum16(dotlr(f3));
        float w0 = __expf(p0), w1 = __expf(p1), w2 = __expf(p2), w3 = __expf(p3);
        l += (w0 + w1) + (w2 + w3);
        acc.x += (w0*f0.x + w1*f1.x) + (w2*f2.x + w3*f3.x);
        acc.y += (w0*f0.y + w1*f1.y) + (w2*f2.y + w3*f3.y);
        acc.z += (w0*f0.z + w1*f1.z) + (w2*f2.z + w3*f3.z);
        acc.w += (w0*f0.w + w1*f1.w) + (w2*f2.w + w3*f3.w);
    }
    for (; i < end; i++) {
        float4 f0 = ldrow(srcs[i]);
        float p0 = rowsum16(dotlr(f0));
        float w0 = __expf(p0);
        l += w0;
        acc.x += w0*f0.x; acc.y += w0*f0.y; acc.z += w0*f0.z; acc.w += w0*f0.w;
    }
    if (act) {
        float inv = 1.f / fmaxf(l, 1e-9f);
        size_t base = (size_t)v * F + off;
        const float4 r4 = *(const float4*)&res[base];
        float4 o4;
        o4.x = acc.x * inv + r4.x + b2f(bias[off]);
        o4.y = acc.y * inv + r4.y + b2f(bias[off + 1]);
        o4.z = acc.z * inv + r4.z + b2f(bias[off + 2]);
        o4.w = acc.w * inv + r4.w + b2f(bias[off + 3]);
        if (do_relu) {
            o4.x = fmaxf(o4.x, 0.f); o4.y = fmaxf(o4.y, 0.f);
            o4.z = fmaxf(o4.z, 0.f); o4.w = fmaxf(o4.w, 0.f);
        }
        *(float4*)&out[base] = o4;
    }
}

// ---------------- batchnorm ----------------

__global__ __launch_bounds__(256) void k_bn_partial(const float* __restrict__ h, float* __restrict__ sum,
                                                    float* __restrict__ sumsq) {
    int c = threadIdx.x;
    int r0 = blockIdx.x * 128;
    int r1 = min(NN, r0 + 128);
    float s = 0.f, ss = 0.f;
    for (int r = r0; r < r1; r++) {
        float vv = h[(size_t)r * HD + c];
        s += vv; ss += vv * vv;
    }
    atomicAdd(&sum[c], s);
    atomicAdd(&sumsq[c], ss);
}

__global__ __launch_bounds__(256) void k_bn_norm(const float* __restrict__ hin, const float* __restrict__ sum,
                                                 const float* __restrict__ sumsq,
                                                 const ushort* __restrict__ g,
                                                 const ushort* __restrict__ be,
                                                 float* __restrict__ hout, ushort* __restrict__ hbf) {
    int idx = blockIdx.x * 256 + threadIdx.x;
    if (idx < NN * HD) {
        int c = idx & (HD - 1);
        float mean = sum[c] * (1.0f / NN);
        float var = fmaxf(sumsq[c] * (1.0f / NN) - mean * mean, 0.f);
        float y = b2f(g[c]) * (hin[idx] - mean) * rsqrtf(var + 1e-5f) + b2f(be[c]);
        y = fmaxf(y, 0.f);
        if (hout) hout[idx] = y;
        hbf[idx] = bf16_of_float(y);
    }
}

// ---------------- head-mean + log_softmax (float32 out) ----------------

__global__ __launch_bounds__(256) void k_final(const float* __restrict__ o2, float* __restrict__ out) {
    int v = blockIdx.x * 4 + (threadIdx.x >> 6);
    int lane = threadIdx.x & 63;
    bool act = lane < CC;
    float z = -1e30f;
    if (act) {
        const float* p = o2 + (size_t)v * HC;
        z = 0.25f * (p[lane] + p[CC + lane] + p[2 * CC + lane] + p[3 * CC + lane]);
    }
    float mx = z;
#pragma unroll
    for (int o = 32; o > 0; o >>= 1) mx = fmaxf(mx, __shfl_xor(mx, o, 64));
    float ex = act ? __expf(z - mx) : 0.f;
    float l = ex;
#pragma unroll
    for (int o = 32; o > 0; o >>= 1) l += __shfl_xor(l, o, 64);
    if (act) out[(size_t)v * CC + lane] = z - mx - logf(fmaxf(l, 1e-30f));
}

// ---------------- driver ----------------

static inline char* alignup(char* p) { return (char*)(((size_t)p + 255) & ~(size_t)255); }

extern "C" void kernel_launch(void* const* d_in, const int* in_sizes, int n_in,
                              void* d_out, int out_size, void* d_ws, size_t ws_size,
                              hipStream_t stream) {
    const float* x     = (const float*)d_in[0];
    const int*  src    = (const int*)d_in[1];
    const int*  dst    = (const int*)d_in[2];
    const float* Wsrc0 = (const float*)d_in[3];
    const float* Wdst0 = (const float*)d_in[4];
    const float* b0    = (const float*)d_in[5];
    const float* attn0 = (const float*)d_in[6];
    const float* resW0 = (const float*)d_in[7];
    const float* Wsrc1 = (const float*)d_in[8];
    const float* Wdst1 = (const float*)d_in[9];
    const float* b1    = (const float*)d_in[10];
    const float* attn1 = (const float*)d_in[11];
    const float* Wsrc2 = (const float*)d_in[12];
    const float* Wdst2 = (const float*)d_in[13];
    const float* b2    = (const float*)d_in[14];
    const float* attn2 = (const float*)d_in[15];
    const float* resW2 = (const float*)d_in[16];
    const float* g0    = (const float*)d_in[17];
    const float* be0   = (const float*)d_in[18];
    const float* g1    = (const float*)d_in[19];
    const float* be1   = (const float*)d_in[20];

    char* w = (char*)d_ws;
    const size_t NF = (size_t)NN * HD;
    float* hA  = (float*)w;  w += NF * 4;
    float* hB  = (float*)w;  w += NF * 4;
    float* res = (float*)w;  w += NF * 4;
    ushort* fsb = (ushort*)w; w += NF * 2;
    ushort* fdb = (ushort*)w; w += NF * 2;
    ushort* hbf = (ushort*)w; w += NF * 2;
    ushort* xc  = (ushort*)w; w += (size_t)NN * INP * 2;
    ushort* bt0 = (ushort*)w; w += 768 * 128 * 2;   // [Wsrc0|Wdst0|resW0]
    ushort* bt1 = (ushort*)w; w += 512 * 256 * 2;   // [Wsrc1|Wdst1]
    ushort* bt2 = (ushort*)w; w += 768 * 256 * 2;   // [Wsrc2|Wdst2|resW2]
    ushort* smallv = (ushort*)w; w += 2368 * 2; w = alignup(w);
    // zeroed in ONE memset: bnstats[1024] + cnt[NN] + pos[NN]
    float* bnstats = (float*)w; w += 1024 * 4;
    int* cnt    = (int*)w; w += NN * 4;
    int* pos    = (int*)w; w += NN * 4; w = alignup(w);
    int* indptr = (int*)w; w += (NN + 1) * 4; w = alignup(w);
    int* srcs   = (int*)w; w += EE * 4;

    const ushort* c_b0    = smallv + 0;
    const ushort* c_attn0 = smallv + 256;
    const ushort* c_b1    = smallv + 512;
    const ushort* c_attn1 = smallv + 768;
    const ushort* c_b2    = smallv + 1024;
    const ushort* c_attn2 = smallv + 1184;
    const ushort* c_g0    = smallv + 1344;
    const ushort* c_be0   = smallv + 1600;
    const ushort* c_g1    = smallv + 1856;
    const ushort* c_be1   = smallv + 2112;

    const int n4 = NN * INP / 4;                    // 960000
    k_cast_all<<<(n4 + 255) / 256 + 1, 256, 0, stream>>>(x, xc, n4,
        b0, attn0, b1, attn1, b2, attn2, g0, be0, g1, be1, smallv);

    hipMemsetAsync(bnstats, 0, (1024 + 2 * NN) * 4, stream);
    k_hist<<<(EE + 255) / 256, 256, 0, stream>>>(dst, cnt);
    k_scan<<<1, 1024, 0, stream>>>(cnt, indptr);
    k_scatter<<<(EE + 255) / 256, 256, 0, stream>>>(src, dst, indptr, pos, srcs);

    k_transpose_all<<<1664, 256, 0, stream>>>(Wsrc0, Wdst0, resW0, Wsrc1, Wdst1,
                                              Wsrc2, Wdst2, resW2, bt0, bt1, bt2);

    const int MB = (NN + 127) / 128;   // 235

    // ---- layer 0: fused 3-matrix GEMM (K=128) ----
    k_gemm_tiled<128, 256><<<dim3(MB, 6), 256, 0, stream>>>(xc, bt0, fsb, fdb, res);
    k_aggregate<DD><<<NN / 4, 256, 0, stream>>>(fsb, fdb, res, c_attn0, c_b0, indptr, srcs, hA, 1);
    k_bn_partial<<<(NN + 127) / 128, 256, 0, stream>>>(hA, bnstats, bnstats + 256);
    k_bn_norm<<<(int)((NF + 255) / 256), 256, 0, stream>>>(hA, bnstats, bnstats + 256,
                                                           c_g0, c_be0, hA, hbf);

    // ---- layer 1: fused 2-matrix GEMM (K=256), identity residual = hA ----
    k_gemm_tiled<256, 256><<<dim3(MB, 4), 256, 0, stream>>>(hbf, bt1, fsb, fdb, nullptr);
    k_aggregate<DD><<<NN / 4, 256, 0, stream>>>(fsb, fdb, hA, c_attn1, c_b1, indptr, srcs, hB, 1);
    k_bn_partial<<<(NN + 127) / 128, 256, 0, stream>>>(hB, bnstats + 512, bnstats + 768);
    k_bn_norm<<<(int)((NF + 255) / 256), 256, 0, stream>>>(hB, bnstats + 512, bnstats + 768,
                                                           c_g1, c_be1, nullptr, hbf);

    // ---- layer 2: fused 3-matrix GEMM (K=256, segN=160) ----
    k_gemm_tiled<256, 160><<<dim3(MB, 6), 256, 0, stream>>>(hbf, bt2, fsb, fdb, res);
    k_aggregate<CC><<<NN / 4, 256, 0, stream>>>(fsb, fdb, res, c_attn2, c_b2, indptr, srcs, hA, 0);

    k_final<<<NN / 4, 256, 0, stream>>>(hA, (float*)d_out);
}

// Round 8
// 479.772 us; speedup vs baseline: 2.3114x; 1.0425x over previous
//
#include <hip/hip_runtime.h>
#include <hip/hip_bf16.h>
#include <math.h>

#define NN 30000
#define EE 400000
#define INP 128
#define HH 4
#define DD 64
#define CC 40
#define HD 256   // H*D
#define HC 160   // H*C

typedef unsigned short ushort;
typedef __attribute__((ext_vector_type(8))) short s8v;   // 8 x bf16 bits (4 VGPRs)
typedef __attribute__((ext_vector_type(4))) float f4v;   // MFMA accumulator

// Inputs: fp32 storage holding bf16-rounded values (established r1-r4).

__device__ inline ushort bf16_of_float(float f) {
    __hip_bfloat16 b = __float2bfloat16(f);
    return *(ushort*)&b;
}
// dword holding 2 packed bf16 -> 2 fp32 (low half, high half)
__device__ __forceinline__ float2 cvt2(unsigned d) {
    return make_float2(__uint_as_float(d << 16), __uint_as_float(d & 0xFFFF0000u));
}
__device__ __forceinline__ float b2f(ushort u) { return __uint_as_float(((unsigned)u) << 16); }

// float2 helpers (packable to v_pk_*_f32)
__device__ __forceinline__ float2 f2add(float2 a, float2 b){ return make_float2(a.x+b.x, a.y+b.y); }
__device__ __forceinline__ float2 f2mul(float2 a, float2 b){ return make_float2(a.x*b.x, a.y*b.y); }
__device__ __forceinline__ float2 f2muls(float2 a, float s){ return make_float2(a.x*s, a.y*s); }
__device__ __forceinline__ float2 f2max(float2 a, float2 b){ return make_float2(fmaxf(a.x,b.x), fmaxf(a.y,b.y)); }
__device__ __forceinline__ float2 f2fma(float2 a, float2 b, float2 c){
    return make_float2(__fmaf_rn(a.x,b.x,c.x), __fmaf_rn(a.y,b.y,c.y));
}

// async 16B global->LDS (dest = wave-uniform base + lane*16)
__device__ __forceinline__ void gld16(const void* g, void* l) {
    __builtin_amdgcn_global_load_lds((const __attribute__((address_space(1))) void*)g,
                                     (__attribute__((address_space(3))) void*)l, 16, 0, 0);
}

// 16-lane DPP row reductions (VALU-only)
__device__ __forceinline__ float rowsum16(float x) {
    int t;
    t = __builtin_amdgcn_update_dpp(0, __float_as_int(x), 0x128, 0xF, 0xF, false); x += __int_as_float(t);
    t = __builtin_amdgcn_update_dpp(0, __float_as_int(x), 0x124, 0xF, 0xF, false); x += __int_as_float(t);
    t = __builtin_amdgcn_update_dpp(0, __float_as_int(x), 0x122, 0xF, 0xF, false); x += __int_as_float(t);
    t = __builtin_amdgcn_update_dpp(0, __float_as_int(x), 0x121, 0xF, 0xF, false); x += __int_as_float(t);
    return x;
}
__device__ __forceinline__ float rowmax16(float x) {
    int t;
    t = __builtin_amdgcn_update_dpp(0, __float_as_int(x), 0x128, 0xF, 0xF, false); x = fmaxf(x, __int_as_float(t));
    t = __builtin_amdgcn_update_dpp(0, __float_as_int(x), 0x124, 0xF, 0xF, false); x = fmaxf(x, __int_as_float(t));
    t = __builtin_amdgcn_update_dpp(0, __float_as_int(x), 0x122, 0xF, 0xF, false); x = fmaxf(x, __int_as_float(t));
    t = __builtin_amdgcn_update_dpp(0, __float_as_int(x), 0x121, 0xF, 0xF, false); x = fmaxf(x, __int_as_float(t));
    return x;
}

// ---------------- fused prep: x-cast + 8 weight transposes + ws zeroing + small-vec cast ----------------
// block ranges: [0,XB) x-cast | [XB,XB+TB) transpose | [XB+TB,XB+TB+ZB) zero | last: smallv
#define XB 3750   // ceil(960000/256)
#define TB 1664   // ceil(425984/256)
#define ZB 239    // ceil(61024/256)

__global__ __launch_bounds__(256) void k_prep(const float* __restrict__ x, ushort* __restrict__ xc,
        const float* W0, const float* W1, const float* W2, const float* W3,
        const float* W4, const float* W5, const float* W6, const float* W7,
        ushort* bt0, ushort* bt1, ushort* bt2,
        int* __restrict__ zero_region,
        const float* b0, const float* a0, const float* b1, const float* a1,
        const float* b2, const float* a2, const float* g0, const float* be0,
        const float* g1, const float* be1, ushort* __restrict__ smallv) {
    int b = blockIdx.x, t = threadIdx.x;
    if (b < XB) {
        int i = b * 256 + t;
        if (i < NN * INP / 4) {
            float4 v = ((const float4*)x)[i];
            ushort4 o;
            o.x = bf16_of_float(v.x); o.y = bf16_of_float(v.y);
            o.z = bf16_of_float(v.z); o.w = bf16_of_float(v.w);
            ((ushort4*)xc)[i] = o;
        }
    } else if (b < XB + TB) {
        const int c0 = 32768, c3 = 98304, seg256 = 65536;
        int g = (b - XB) * 256 + t;               // < 425984
        if (g < 425984) {
            const float* Ws[8] = {W0, W1, W2, W3, W4, W5, W6, W7};
            int seg, local, K, No;
            ushort* dst;
            if (g < c3) {
                seg = g / c0; local = g - seg * c0; K = 128; No = 256;
                dst = bt0 + seg * c0;
            } else {
                int gg = g - c3;
                int s5 = gg / seg256; local = gg - s5 * seg256; seg = 3 + s5; K = 256;
                No = (seg >= 5) ? 160 : 256;
                dst = (seg < 5) ? bt1 + (seg - 3) * seg256 : bt2 + (seg - 5) * seg256;
            }
            int n = (K == 128) ? (local >> 7) : (local >> 8);
            int k = local & (K - 1);
            dst[local] = (n < No) ? bf16_of_float(Ws[seg][k * No + n]) : (ushort)0;
        }
    } else if (b < XB + TB + ZB) {
        int i = (b - XB - TB) * 256 + t;
        if (i < 1024 + 2 * NN) zero_region[i] = 0;   // bnstats + cnt + pos
    } else {
        const float* ptrs[10] = {b0, a0, b1, a1, b2, a2, g0, be0, g1, be1};
        const int sz[10] = {256, 256, 256, 256, 160, 160, 256, 256, 256, 256};
        int off = 0;
        for (int j = 0; j < 10; j++) {
            if (t < sz[j]) smallv[off + t] = bf16_of_float(ptrs[j][t]);
            off += sz[j];
        }
    }
}

// ---------------- CSR build ----------------

__global__ __launch_bounds__(256) void k_hist(const int* __restrict__ dst, int* __restrict__ cnt) {
    int e = blockIdx.x * 256 + threadIdx.x;
    if (e < EE) atomicAdd(&cnt[dst[e]], 1);
}

__global__ __launch_bounds__(1024) void k_scan(const int* __restrict__ cnt, int* __restrict__ indptr) {
    __shared__ int ss[1024];
    int t = threadIdx.x;
    const int CH = 30;
    int b = t * CH;
    int e2 = min(NN, b + CH);
    int s = 0;
    for (int i = b; i < e2; i++) s += cnt[i];
    ss[t] = s;
    __syncthreads();
    for (int o = 1; o < 1024; o <<= 1) {
        int v = (t >= o) ? ss[t - o] : 0;
        __syncthreads();
        ss[t] += v;
        __syncthreads();
    }
    int run = ss[t] - s;
    for (int i = b; i < e2; i++) { indptr[i] = run; run += cnt[i]; }
    if (t == 0) indptr[NN] = EE;
}

__global__ __launch_bounds__(256) void k_scatter(const int* __restrict__ src, const int* __restrict__ dst,
                                                 const int* __restrict__ indptr, int* __restrict__ pos,
                                                 int* __restrict__ srcs) {
    int e = blockIdx.x * 256 + threadIdx.x;
    if (e < EE) {
        int d = dst[e];
        int p = atomicAdd(&pos[d], 1);
        srcs[indptr[d] + p] = src[e];
    }
}

// ---------------- tiled bf16 MFMA GEMM, compile-time K / segN (r7, passing) ----------------

template<int K, int SEGN>
__global__ __launch_bounds__(256) void k_gemm_tiled(const ushort* __restrict__ A,
                                                    const ushort* __restrict__ Bt,
                                                    ushort* __restrict__ out0, ushort* __restrict__ out1,
                                                    float* __restrict__ out2) {
    __shared__ ushort As[128 * 32];   // chunk c (16B) at byte c*16; row = c>>2, kpart = c&3
    __shared__ ushort Bs[128 * 32];
    int t = threadIdx.x;
    int wave = t >> 6, lane = t & 63;
    int m = lane & 15, q = lane >> 4;
    int row0 = blockIdx.x * 128, col0 = blockIdx.y * 128;
    int wr = (wave >> 1) << 6, wc = (wave & 1) << 6;
    f4v acc[4][4] = {};
    int c1 = t, c2 = t + 256;
    int ar1 = min(row0 + (c1 >> 2), NN - 1);
    int ar2 = min(row0 + (c2 >> 2), NN - 1);
    const ushort* a1 = A + (size_t)ar1 * K + (c1 & 3) * 8;
    const ushort* a2 = A + (size_t)ar2 * K + (c2 & 3) * 8;
    const ushort* b1 = Bt + (size_t)(col0 + (c1 >> 2)) * K + (c1 & 3) * 8;
    const ushort* b2 = Bt + (size_t)(col0 + (c2 >> 2)) * K + (c2 & 3) * 8;
    int wbase = wave << 10;
    char* AsB = (char*)As;
    char* BsB = (char*)Bs;

#pragma unroll
    for (int kt = 0; kt < K; kt += 32) {
        __syncthreads();
        gld16(a1 + kt, AsB + wbase);
        gld16(a2 + kt, AsB + 4096 + wbase);
        gld16(b1 + kt, BsB + wbase);
        gld16(b2 + kt, BsB + 4096 + wbase);
        __syncthreads();
        s8v af[4], bg[4];
#pragma unroll
        for (int i = 0; i < 4; i++) af[i] = *(const s8v*)&As[(wr + i * 16 + m) * 32 + q * 8];
#pragma unroll
        for (int c = 0; c < 4; c++) bg[c] = *(const s8v*)&Bs[(wc + c * 16 + m) * 32 + q * 8];
#pragma unroll
        for (int i = 0; i < 4; i++)
#pragma unroll
            for (int c = 0; c < 4; c++)
                acc[i][c] = __builtin_amdgcn_mfma_f32_16x16x32_bf16(af[i], bg[c], acc[i][c], 0, 0, 0);
    }

#pragma unroll
    for (int c = 0; c < 4; c++) {
        int gcb = col0 + wc + c * 16;
        int seg = gcb >> 8;
        int scb = (gcb & 255) + m;
        if (scb < SEGN) {
            if (seg < 2) {
                ushort* op = seg == 0 ? out0 : out1;
#pragma unroll
                for (int i = 0; i < 4; i++) {
                    int gr0 = row0 + wr + i * 16 + q * 4;
#pragma unroll
                    for (int r = 0; r < 4; r++) {
                        int gr = gr0 + r;
                        if (gr < NN) op[(size_t)gr * SEGN + scb] = bf16_of_float(acc[i][c][r]);
                    }
                }
            } else {
#pragma unroll
                for (int i = 0; i < 4; i++) {
                    int gr0 = row0 + wr + i * 16 + q * 4;
#pragma unroll
                    for (int r = 0; r < 4; r++) {
                        int gr = gr0 + r;
                        if (gr < NN) out2[(size_t)gr * SEGN + scb] = acc[i][c][r];
                    }
                }
            }
        }
    }
}

// ---------------- fused GATv2 edge phase, packed fp32 math ----------------
// One wave per dst node, all 4 heads. lane=16h+j holds dims [4j..4j+3] of head h
// as two float2. leaky(t)=max(t,0.2t). DPP row reduce. FINAL fuses head-mean+log_softmax.

template<int DH, bool FINAL>
__global__ __launch_bounds__(256) void k_aggregate(const ushort* __restrict__ fs, const ushort* __restrict__ fd,
                                                   const float* __restrict__ res,
                                                   const ushort* __restrict__ attn,
                                                   const ushort* __restrict__ bias,
                                                   const int* __restrict__ indptr, const int* __restrict__ srcs,
                                                   float* __restrict__ out, int do_relu) {
    constexpr int F = HH * DH;
    constexpr int JMAX = DH >> 2;
    int v = __builtin_amdgcn_readfirstlane(blockIdx.x * 4 + (threadIdx.x >> 6));
    int lane = threadIdx.x & 63;
    int h = lane >> 4, j = lane & 15;
    bool act = j < JMAX;
    int off = h * DH + 4 * j;
    float2 fda = {0.f,0.f}, fdb = {0.f,0.f}, ava = {0.f,0.f}, avb = {0.f,0.f};
    if (act) {
        uint2 d = *(const uint2*)&fd[(size_t)v * F + off];
        fda = cvt2(d.x); fdb = cvt2(d.y);
        uint2 a = *(const uint2*)&attn[off];
        ava = cvt2(a.x); avb = cvt2(a.y);
    }
    float l = 0.f;
    float2 acca = {0.f,0.f}, accb = {0.f,0.f};
    int beg = indptr[v], end = indptr[v + 1];

    auto ldrow = [&](int u, float2& ra, float2& rb) {
        ra = make_float2(0.f, 0.f); rb = make_float2(0.f, 0.f);
        if (act) {
            uint2 d = *(const uint2*)&fs[(size_t)u * F + off];
            ra = cvt2(d.x); rb = cvt2(d.y);
        }
    };
    auto dotlr = [&](const float2& ra, const float2& rb) -> float {
        float2 t0 = f2add(ra, fda);
        float2 t1 = f2add(rb, fdb);
        t0 = f2max(t0, f2muls(t0, 0.2f));      // leaky_relu slope 0.2 == max(t, 0.2t)
        t1 = f2max(t1, f2muls(t1, 0.2f));
        float2 p2 = f2mul(ava, t0);
        p2 = f2fma(avb, t1, p2);
        return p2.x + p2.y;
    };

    int i = beg;
    for (; i + 3 < end; i += 4) {
        int u0 = srcs[i], u1 = srcs[i+1], u2 = srcs[i+2], u3 = srcs[i+3];
        float2 r0a, r0b, r1a, r1b, r2a, r2b, r3a, r3b;
        ldrow(u0, r0a, r0b); ldrow(u1, r1a, r1b);
        ldrow(u2, r2a, r2b); ldrow(u3, r3a, r3b);
        float p0 = rowsum16(dotlr(r0a, r0b));
        float p1 = rowsum16(dotlr(r1a, r1b));
        float p2 = rowsum16(dotlr(r2a, r2b));
        float p3 = rowsum16(dotlr(r3a, r3b));
        float w0 = __expf(p0), w1 = __expf(p1), w2 = __expf(p2), w3 = __expf(p3);
        l += (w0 + w1) + (w2 + w3);
        acca = f2fma(make_float2(w0, w0), r0a, acca);
        accb = f2fma(make_float2(w0, w0), r0b, accb);
        acca = f2fma(make_float2(w1, w1), r1a, acca);
        accb = f2fma(make_float2(w1, w1), r1b, accb);
        acca = f2fma(make_float2(w2, w2), r2a, acca);
        accb = f2fma(make_float2(w2, w2), r2b, accb);
        acca = f2fma(make_float2(w3, w3), r3a, acca);
        accb = f2fma(make_float2(w3, w3), r3b, accb);
    }
    for (; i < end; i++) {
        float2 ra, rb;
        ldrow(srcs[i], ra, rb);
        float p0 = rowsum16(dotlr(ra, rb));
        float w0 = __expf(p0);
        l += w0;
        acca = f2fma(make_float2(w0, w0), ra, acca);
        accb = f2fma(make_float2(w0, w0), rb, accb);
    }

    float4 o4 = {0.f, 0.f, 0.f, 0.f};
    if (act) {
        float inv = 1.f / fmaxf(l, 1e-9f);
        size_t base = (size_t)v * F + off;
        float4 r4 = *(const float4*)&res[base];
        uint2 bb = *(const uint2*)&bias[off];
        float2 bl = cvt2(bb.x), bh = cvt2(bb.y);
        o4.x = acca.x * inv + r4.x + bl.x;
        o4.y = acca.y * inv + r4.y + bl.y;
        o4.z = accb.x * inv + r4.z + bh.x;
        o4.w = accb.y * inv + r4.w + bh.y;
    }
    if (!FINAL) {
        if (act) {
            if (do_relu) {
                o4.x = fmaxf(o4.x, 0.f); o4.y = fmaxf(o4.y, 0.f);
                o4.z = fmaxf(o4.z, 0.f); o4.w = fmaxf(o4.w, 0.f);
            }
            *(float4*)&out[(size_t)v * F + off] = o4;
        }
    } else {
        // head mean: sum over the 4 head groups (lanes 16/32 apart, same j)
#pragma unroll
        for (int msk = 16; msk <= 32; msk <<= 1) {
            o4.x += __shfl_xor(o4.x, msk, 64);
            o4.y += __shfl_xor(o4.y, msk, 64);
            o4.z += __shfl_xor(o4.z, msk, 64);
            o4.w += __shfl_xor(o4.w, msk, 64);
        }
        float4 zv = make_float4(0.25f * o4.x, 0.25f * o4.y, 0.25f * o4.z, 0.25f * o4.w);
        float mx4 = act ? fmaxf(fmaxf(zv.x, zv.y), fmaxf(zv.z, zv.w)) : -1e30f;
        float mx = rowmax16(mx4);
        float es = 0.f;
        if (act) es = __expf(zv.x - mx) + __expf(zv.y - mx) + __expf(zv.z - mx) + __expf(zv.w - mx);
        float ssum = rowsum16(es);
        float lse = mx + logf(ssum);
        if (act && h == 0) {
            float4 w4 = make_float4(zv.x - lse, zv.y - lse, zv.z - lse, zv.w - lse);
            *(float4*)&out[(size_t)v * CC + 4 * j] = w4;
        }
    }
}

// ---------------- batchnorm ----------------

__global__ __launch_bounds__(256) void k_bn_partial(const float* __restrict__ h, float* __restrict__ sum,
                                                    float* __restrict__ sumsq) {
    int c = threadIdx.x;
    int r0 = blockIdx.x * 128;
    int r1 = min(NN, r0 + 128);
    float s = 0.f, ss = 0.f;
    for (int r = r0; r < r1; r++) {
        float vv = h[(size_t)r * HD + c];
        s += vv; ss += vv * vv;
    }
    atomicAdd(&sum[c], s);
    atomicAdd(&sumsq[c], ss);
}

__global__ __launch_bounds__(256) void k_bn_norm(const float* __restrict__ hin, const float* __restrict__ sum,
                                                 const float* __restrict__ sumsq,
                                                 const ushort* __restrict__ g,
                                                 const ushort* __restrict__ be,
                                                 float* __restrict__ hout, ushort* __restrict__ hbf) {
    int idx = blockIdx.x * 256 + threadIdx.x;
    if (idx < NN * HD) {
        int c = idx & (HD - 1);
        float mean = sum[c] * (1.0f / NN);
        float var = fmaxf(sumsq[c] * (1.0f / NN) - mean * mean, 0.f);
        float y = b2f(g[c]) * (hin[idx] - mean) * rsqrtf(var + 1e-5f) + b2f(be[c]);
        y = fmaxf(y, 0.f);
        if (hout) hout[idx] = y;
        hbf[idx] = bf16_of_float(y);
    }
}

// ---------------- driver ----------------

static inline char* alignup(char* p) { return (char*)(((size_t)p + 255) & ~(size_t)255); }

extern "C" void kernel_launch(void* const* d_in, const int* in_sizes, int n_in,
                              void* d_out, int out_size, void* d_ws, size_t ws_size,
                              hipStream_t stream) {
    const float* x     = (const float*)d_in[0];
    const int*  src    = (const int*)d_in[1];
    const int*  dst    = (const int*)d_in[2];
    const float* Wsrc0 = (const float*)d_in[3];
    const float* Wdst0 = (const float*)d_in[4];
    const float* b0    = (const float*)d_in[5];
    const float* attn0 = (const float*)d_in[6];
    const float* resW0 = (const float*)d_in[7];
    const float* Wsrc1 = (const float*)d_in[8];
    const float* Wdst1 = (const float*)d_in[9];
    const float* b1    = (const float*)d_in[10];
    const float* attn1 = (const float*)d_in[11];
    const float* Wsrc2 = (const float*)d_in[12];
    const float* Wdst2 = (const float*)d_in[13];
    const float* b2    = (const float*)d_in[14];
    const float* attn2 = (const float*)d_in[15];
    const float* resW2 = (const float*)d_in[16];
    const float* g0    = (const float*)d_in[17];
    const float* be0   = (const float*)d_in[18];
    const float* g1    = (const float*)d_in[19];
    const float* be1   = (const float*)d_in[20];

    char* w = (char*)d_ws;
    const size_t NF = (size_t)NN * HD;
    float* hA  = (float*)w;  w += NF * 4;
    float* hB  = (float*)w;  w += NF * 4;
    float* res = (float*)w;  w += NF * 4;
    ushort* fsb = (ushort*)w; w += NF * 2;
    ushort* fdb = (ushort*)w; w += NF * 2;
    ushort* hbf = (ushort*)w; w += NF * 2;
    ushort* xc  = (ushort*)w; w += (size_t)NN * INP * 2;
    ushort* bt0 = (ushort*)w; w += 768 * 128 * 2;   // [Wsrc0|Wdst0|resW0]
    ushort* bt1 = (ushort*)w; w += 512 * 256 * 2;   // [Wsrc1|Wdst1]
    ushort* bt2 = (ushort*)w; w += 768 * 256 * 2;   // [Wsrc2|Wdst2|resW2]
    ushort* smallv = (ushort*)w; w += 2368 * 2; w = alignup(w);
    // zeroed in k_prep: bnstats[1024] + cnt[NN] + pos[NN] (contiguous)
    float* bnstats = (float*)w; w += 1024 * 4;
    int* cnt    = (int*)w; w += NN * 4;
    int* pos    = (int*)w; w += NN * 4; w = alignup(w);
    int* indptr = (int*)w; w += (NN + 1) * 4; w = alignup(w);
    int* srcs   = (int*)w; w += EE * 4;

    const ushort* c_b0    = smallv + 0;
    const ushort* c_attn0 = smallv + 256;
    const ushort* c_b1    = smallv + 512;
    const ushort* c_attn1 = smallv + 768;
    const ushort* c_b2    = smallv + 1024;
    const ushort* c_attn2 = smallv + 1184;
    const ushort* c_g0    = smallv + 1344;
    const ushort* c_be0   = smallv + 1600;
    const ushort* c_g1    = smallv + 1856;
    const ushort* c_be1   = smallv + 2112;

    // 1: fused prep (x-cast, weight transposes, ws zero, small-vec cast)
    k_prep<<<XB + TB + ZB + 1, 256, 0, stream>>>(x, xc,
        Wsrc0, Wdst0, resW0, Wsrc1, Wdst1, Wsrc2, Wdst2, resW2, bt0, bt1, bt2,
        (int*)bnstats,
        b0, attn0, b1, attn1, b2, attn2, g0, be0, g1, be1, smallv);

    // 2-4: CSR build
    k_hist<<<(EE + 255) / 256, 256, 0, stream>>>(dst, cnt);
    k_scan<<<1, 1024, 0, stream>>>(cnt, indptr);
    k_scatter<<<(EE + 255) / 256, 256, 0, stream>>>(src, dst, indptr, pos, srcs);

    const int MB = (NN + 127) / 128;   // 235

    // 5-8: layer 0
    k_gemm_tiled<128, 256><<<dim3(MB, 6), 256, 0, stream>>>(xc, bt0, fsb, fdb, res);
    k_aggregate<DD, false><<<NN / 4, 256, 0, stream>>>(fsb, fdb, res, c_attn0, c_b0, indptr, srcs, hA, 1);
    k_bn_partial<<<(NN + 127) / 128, 256, 0, stream>>>(hA, bnstats, bnstats + 256);
    k_bn_norm<<<(int)((NF + 255) / 256), 256, 0, stream>>>(hA, bnstats, bnstats + 256,
                                                           c_g0, c_be0, hA, hbf);

    // 9-12: layer 1 (identity residual = hA)
    k_gemm_tiled<256, 256><<<dim3(MB, 4), 256, 0, stream>>>(hbf, bt1, fsb, fdb, nullptr);
    k_aggregate<DD, false><<<NN / 4, 256, 0, stream>>>(fsb, fdb, hA, c_attn1, c_b1, indptr, srcs, hB, 1);
    k_bn_partial<<<(NN + 127) / 128, 256, 0, stream>>>(hB, bnstats + 512, bnstats + 768);
    k_bn_norm<<<(int)((NF + 255) / 256), 256, 0, stream>>>(hB, bnstats + 512, bnstats + 768,
                                                           c_g1, c_be1, nullptr, hbf);

    // 13-14: layer 2 + fused head-mean/log_softmax -> d_out
    k_gemm_tiled<256, 160><<<dim3(MB, 6), 256, 0, stream>>>(hbf, bt2, fsb, fdb, res);
    k_aggregate<CC, true><<<NN / 4, 256, 0, stream>>>(fsb, fdb, res, c_attn2, c_b2, indptr, srcs,
                                                      (float*)d_out, 0);
}